// Round 1
// baseline (1223.464 us; speedup 1.0000x reference)
//
#include <hip/hip_runtime.h>

#define NPIX 4096
#define NCH 72
#define NCHUNK 18

static constexpr float SCALE_LOG2E = 0.022542110013890054f; // (1/64)*log2(e)

// ws layout (float offsets)
#define OFF_QC 0          // [18][4096][4]  (scaled by SCALE_LOG2E)
#define OFF_KC 294912     // [18][4096][4]
#define OFF_VC 589824     // [18][4096][4]
#define OFF_WC 884736     // [18][4096][4]  v/D
#define OFF_QG 1179648    // [4096][72]     (scaled)
#define OFF_KG 1474560    // [4096][72]
#define OFF_VG 1769472    // [4096][72]
#define OFF_WG 2064384    // [4096][72]     v/D
#define OFF_DC 2359296    // [18][4096]
#define OFF_DG 2433024    // [4096]
#define OFF_OUTC 2437120  // [18][4096][4]
#define OFF_OUTG 2732032  // [4096][72]
#define WS_FLOATS 3026944

__device__ __forceinline__ float fexp2(float x) {
#if __has_builtin(__builtin_amdgcn_exp2f)
  return __builtin_amdgcn_exp2f(x);
#else
  return exp2f(x);
#endif
}

__device__ __forceinline__ float dot4(float4 a, float4 b) {
  return a.x*b.x + a.y*b.y + a.z*b.z + a.w*b.w;
}

__device__ __forceinline__ float4 mix4(const float* __restrict__ W, const float* __restrict__ b,
                                       float x0, float x1, float x2, float x3, float sc)
{
  float4 r;
  r.x = (b[0] + W[0]*x0  + W[1]*x1  + W[2]*x2  + W[3]*x3)  * sc;
  r.y = (b[1] + W[4]*x0  + W[5]*x1  + W[6]*x2  + W[7]*x3)  * sc;
  r.z = (b[2] + W[8]*x0  + W[9]*x1  + W[10]*x2 + W[11]*x3) * sc;
  r.w = (b[3] + W[12]*x0 + W[13]*x1 + W[14]*x2 + W[15]*x3) * sc;
  return r;
}

// grid (16, 10) x 256. seg 0: chunk qkv. seg 1..9: global (mat m, out-ch group g of 24)
__global__ void k_qkv(const float* __restrict__ x,
    const float* __restrict__ Wq, const float* __restrict__ bq,
    const float* __restrict__ Wk, const float* __restrict__ bk,
    const float* __restrict__ Wv, const float* __restrict__ bv,
    const float* __restrict__ WqG, const float* __restrict__ bqG,
    const float* __restrict__ WkG, const float* __restrict__ bkG,
    const float* __restrict__ WvG, const float* __restrict__ bvG,
    float* __restrict__ ws)
{
  const int p = blockIdx.x * blockDim.x + threadIdx.x;
  const int seg = blockIdx.y;
  if (seg == 0) {
    float4* qd = reinterpret_cast<float4*>(ws + OFF_QC);
    float4* kd = reinterpret_cast<float4*>(ws + OFF_KC);
    float4* vd = reinterpret_cast<float4*>(ws + OFF_VC);
    for (int n = 0; n < NCHUNK; ++n) {
      const float x0 = x[(4*n+0)*NPIX + p];
      const float x1 = x[(4*n+1)*NPIX + p];
      const float x2 = x[(4*n+2)*NPIX + p];
      const float x3 = x[(4*n+3)*NPIX + p];
      float4 q = mix4(Wq + n*16, bq + n*4, x0, x1, x2, x3, SCALE_LOG2E);
      float4 k = mix4(Wk + n*16, bk + n*4, x0, x1, x2, x3, 1.0f);
      float4 v = mix4(Wv + n*16, bv + n*4, x0, x1, x2, x3, 1.0f);
      qd[n*NPIX + p] = q;
      kd[n*NPIX + p] = k;
      vd[n*NPIX + p] = v;
    }
  } else {
    const int m = (seg - 1) / 3;
    const int g = (seg - 1) % 3;
    const float* W = (m == 0) ? WqG : (m == 1) ? WkG : WvG;
    const float* b = (m == 0) ? bqG : (m == 1) ? bkG : bvG;
    float* dst = ws + ((m == 0) ? OFF_QG : (m == 1) ? OFF_KG : OFF_VG);
    float xv[NCH];
#pragma unroll
    for (int c = 0; c < NCH; ++c) xv[c] = x[c*NPIX + p];
    const int ob = g * 24;
    for (int o = ob; o < ob + 24; ++o) {
      float acc = b[o];
      const float* wrow = W + o*NCH;
#pragma unroll
      for (int c = 0; c < NCH; ++c) acc += wrow[c]*xv[c];
      if (m == 0) acc *= SCALE_LOG2E;
      dst[p*NCH + o] = acc;
    }
  }
}

// chunk pass A: D_j = sum_i exp2(q_j . k_i).  grid (4, 18, 8) x 256, thread owns 4 j's
__global__ void k_chunkA(float* __restrict__ ws)
{
  const int n = blockIdx.y;
  const int jq = blockIdx.x * blockDim.x + threadIdx.x; // 0..1023
  const int j0 = jq * 4;
  const float4* qc = reinterpret_cast<const float4*>(ws + OFF_QC) + n*NPIX;
  const float4* kc = reinterpret_cast<const float4*>(ws + OFF_KC) + n*NPIX;
  float4 q0 = qc[j0+0], q1 = qc[j0+1], q2 = qc[j0+2], q3 = qc[j0+3];
  float d0 = 0.f, d1 = 0.f, d2 = 0.f, d3 = 0.f;
  const int ib = blockIdx.z * 512;
#pragma unroll 4
  for (int i = ib; i < ib + 512; ++i) {
    float4 k = kc[i];
    d0 += fexp2(dot4(q0, k));
    d1 += fexp2(dot4(q1, k));
    d2 += fexp2(dot4(q2, k));
    d3 += fexp2(dot4(q3, k));
  }
  float* Dc = ws + OFF_DC + n*NPIX;
  atomicAdd(&Dc[j0+0], d0);
  atomicAdd(&Dc[j0+1], d1);
  atomicAdd(&Dc[j0+2], d2);
  atomicAdd(&Dc[j0+3], d3);
}

// global pass A: DG_j = sum_i exp2(qG_j . kG_i).  grid (16, 1, 32) x 256
__global__ void k_gA(float* __restrict__ ws)
{
  const int j = blockIdx.x * blockDim.x + threadIdx.x;
  const float* qg = ws + OFF_QG + j*NCH;
  float q[NCH];
#pragma unroll
  for (int c = 0; c < NCH; ++c) q[c] = qg[c];
  float d = 0.f;
  const int ib = blockIdx.z * 128;
  for (int i = ib; i < ib + 128; ++i) {
    const float* kg = ws + OFF_KG + i*NCH; // uniform address -> scalar/broadcast loads
    float s = 0.f;
#pragma unroll
    for (int c = 0; c < NCH; ++c) s += q[c]*kg[c];
    d += fexp2(s);
  }
  atomicAdd(ws + OFF_DG + j, d);
}

// w = v / D for both chunk and global.  grid (304) x 256
__global__ void k_wcomp(float* __restrict__ ws)
{
  const int t = blockIdx.x * blockDim.x + threadIdx.x;
  if (blockIdx.x < 288) {
    const int n = t >> 12, j = t & 4095;
    const float inv = 1.0f / ws[OFF_DC + n*NPIX + j];
    float4 v = reinterpret_cast<const float4*>(ws + OFF_VC)[n*NPIX + j];
    v.x *= inv; v.y *= inv; v.z *= inv; v.w *= inv;
    reinterpret_cast<float4*>(ws + OFF_WC)[n*NPIX + j] = v;
  } else {
    const int j = t - NCHUNK*NPIX; // 0..4095
    const float inv = 1.0f / ws[OFF_DG + j];
#pragma unroll
    for (int c = 0; c < NCH; c += 4) {
      float4 v = *reinterpret_cast<const float4*>(ws + OFF_VG + j*NCH + c);
      v.x *= inv; v.y *= inv; v.z *= inv; v.w *= inv;
      *reinterpret_cast<float4*>(ws + OFF_WG + j*NCH + c) = v;
    }
  }
}

// chunk pass B: outC[n][i][c] += sum_j w[c][j]*exp2(q_j.k_i).  grid (4, 18, 8) x 256, thread owns 4 i's
__global__ void k_chunkB(float* __restrict__ ws)
{
  const int n = blockIdx.y;
  const int iq = blockIdx.x * blockDim.x + threadIdx.x;
  const int i0 = iq * 4;
  const float4* kc = reinterpret_cast<const float4*>(ws + OFF_KC) + n*NPIX;
  const float4* qc = reinterpret_cast<const float4*>(ws + OFF_QC) + n*NPIX;
  const float4* wc = reinterpret_cast<const float4*>(ws + OFF_WC) + n*NPIX;
  float4 k0 = kc[i0+0], k1 = kc[i0+1], k2 = kc[i0+2], k3 = kc[i0+3];
  float4 a0 = {0,0,0,0}, a1 = {0,0,0,0}, a2 = {0,0,0,0}, a3 = {0,0,0,0};
  const int jb = blockIdx.z * 512;
#pragma unroll 2
  for (int j = jb; j < jb + 512; ++j) {
    float4 q = qc[j];
    float4 w = wc[j];
    float e0 = fexp2(dot4(q, k0));
    float e1 = fexp2(dot4(q, k1));
    float e2 = fexp2(dot4(q, k2));
    float e3 = fexp2(dot4(q, k3));
    a0.x += e0*w.x; a0.y += e0*w.y; a0.z += e0*w.z; a0.w += e0*w.w;
    a1.x += e1*w.x; a1.y += e1*w.y; a1.z += e1*w.z; a1.w += e1*w.w;
    a2.x += e2*w.x; a2.y += e2*w.y; a2.z += e2*w.z; a2.w += e2*w.w;
    a3.x += e3*w.x; a3.y += e3*w.y; a3.z += e3*w.z; a3.w += e3*w.w;
  }
  float* oc = ws + OFF_OUTC;
  atomicAdd(&oc[(n*NPIX + i0+0)*4 + 0], a0.x);
  atomicAdd(&oc[(n*NPIX + i0+0)*4 + 1], a0.y);
  atomicAdd(&oc[(n*NPIX + i0+0)*4 + 2], a0.z);
  atomicAdd(&oc[(n*NPIX + i0+0)*4 + 3], a0.w);
  atomicAdd(&oc[(n*NPIX + i0+1)*4 + 0], a1.x);
  atomicAdd(&oc[(n*NPIX + i0+1)*4 + 1], a1.y);
  atomicAdd(&oc[(n*NPIX + i0+1)*4 + 2], a1.z);
  atomicAdd(&oc[(n*NPIX + i0+1)*4 + 3], a1.w);
  atomicAdd(&oc[(n*NPIX + i0+2)*4 + 0], a2.x);
  atomicAdd(&oc[(n*NPIX + i0+2)*4 + 1], a2.y);
  atomicAdd(&oc[(n*NPIX + i0+2)*4 + 2], a2.z);
  atomicAdd(&oc[(n*NPIX + i0+2)*4 + 3], a2.w);
  atomicAdd(&oc[(n*NPIX + i0+3)*4 + 0], a3.x);
  atomicAdd(&oc[(n*NPIX + i0+3)*4 + 1], a3.y);
  atomicAdd(&oc[(n*NPIX + i0+3)*4 + 2], a3.z);
  atomicAdd(&oc[(n*NPIX + i0+3)*4 + 3], a3.w);
}

// global pass B: outG[i][c] += sum_j wG[j][c]*exp2(qG_j . kG_i).  grid (16, 1, 32) x 256
__global__ void k_gB(float* __restrict__ ws)
{
  const int i = blockIdx.x * blockDim.x + threadIdx.x;
  const float* kg = ws + OFF_KG + i*NCH;
  float k[NCH];
#pragma unroll
  for (int c = 0; c < NCH; ++c) k[c] = kg[c];
  float acc[NCH];
#pragma unroll
  for (int c = 0; c < NCH; ++c) acc[c] = 0.f;
  const int jb = blockIdx.z * 128;
  for (int j = jb; j < jb + 128; ++j) {
    const float* qg = ws + OFF_QG + j*NCH; // uniform
    const float* wg = ws + OFF_WG + j*NCH; // uniform
    float s = 0.f;
#pragma unroll
    for (int c = 0; c < NCH; ++c) s += k[c]*qg[c];
    float e = fexp2(s);
#pragma unroll
    for (int c = 0; c < NCH; ++c) acc[c] += e*wg[c];
  }
  float* og = ws + OFF_OUTG + i*NCH;
#pragma unroll
  for (int c = 0; c < NCH; ++c) atomicAdd(&og[c], acc[c]);
}

// pooled[n][p] = sum_c x[4n+c][p] * (outC[n][p][c] + outG[p][4n+c]).  grid (288) x 256
__global__ void k_final(const float* __restrict__ x, const float* __restrict__ ws,
                        float* __restrict__ out)
{
  const int t = blockIdx.x * blockDim.x + threadIdx.x;
  const int n = t >> 12, p = t & 4095;
  float4 oc = reinterpret_cast<const float4*>(ws + OFF_OUTC)[t];
  const float* og = ws + OFF_OUTG + p*NCH + n*4;
  float s = x[(4*n+0)*NPIX + p] * (oc.x + og[0])
          + x[(4*n+1)*NPIX + p] * (oc.y + og[1])
          + x[(4*n+2)*NPIX + p] * (oc.z + og[2])
          + x[(4*n+3)*NPIX + p] * (oc.w + og[3]);
  out[t] = s;
}

extern "C" void kernel_launch(void* const* d_in, const int* in_sizes, int n_in,
                              void* d_out, int out_size, void* d_ws, size_t ws_size,
                              hipStream_t stream)
{
  const float* x   = (const float*)d_in[0];
  const float* Wq  = (const float*)d_in[1];
  const float* bq  = (const float*)d_in[2];
  const float* Wk  = (const float*)d_in[3];
  const float* bk  = (const float*)d_in[4];
  const float* Wv  = (const float*)d_in[5];
  const float* bv  = (const float*)d_in[6];
  const float* WqG = (const float*)d_in[7];
  const float* bqG = (const float*)d_in[8];
  const float* WkG = (const float*)d_in[9];
  const float* bkG = (const float*)d_in[10];
  const float* WvG = (const float*)d_in[11];
  const float* bvG = (const float*)d_in[12];
  float* ws  = (float*)d_ws;
  float* out = (float*)d_out;

  if (ws_size < (size_t)WS_FLOATS * sizeof(float)) return; // need ~12.1 MB scratch

  // zero accumulators (Dc, DG, outC, outG are contiguous at the tail)
  hipMemsetAsync(ws + OFF_DC, 0, (size_t)(WS_FLOATS - OFF_DC) * sizeof(float), stream);

  hipLaunchKernelGGL(k_qkv, dim3(16, 10), dim3(256), 0, stream,
                     x, Wq, bq, Wk, bk, Wv, bv, WqG, bqG, WkG, bkG, WvG, bvG, ws);
  hipLaunchKernelGGL(k_chunkA, dim3(4, 18, 8), dim3(256), 0, stream, ws);
  hipLaunchKernelGGL(k_gA, dim3(16, 1, 32), dim3(256), 0, stream, ws);
  hipLaunchKernelGGL(k_wcomp, dim3(304), dim3(256), 0, stream, ws);
  hipLaunchKernelGGL(k_chunkB, dim3(4, 18, 8), dim3(256), 0, stream, ws);
  hipLaunchKernelGGL(k_gB, dim3(16, 1, 32), dim3(256), 0, stream, ws);
  hipLaunchKernelGGL(k_final, dim3(288), dim3(256), 0, stream, x, ws, out);
}

// Round 2
// 789.616 us; speedup vs baseline: 1.5494x; 1.5494x over previous
//
#include <hip/hip_runtime.h>

#define NPIX 4096
#define NCH 72
#define NCHUNK 18

static constexpr float SCALE_LOG2E = 0.022542110013890054f; // (1/64)*log2(e)

// ws layout (float offsets)
#define OFF_QC 0          // [18][4096][4]  (scaled by SCALE_LOG2E)
#define OFF_KC 294912     // [18][4096][4]
#define OFF_VC 589824     // [18][4096][4]
#define OFF_WC 884736     // [18][4096][4]  v/D
#define OFF_QG 1179648    // [4096][72]     (scaled)
#define OFF_KG 1474560    // [4096][72]
#define OFF_VG 1769472    // [4096][72]
#define OFF_WG 2064384    // [4096][72]     v/D
#define OFF_DC 2359296    // [18][4096]
#define OFF_DG 2433024    // [4096]
#define OFF_OUTC 2437120  // [18][4][4096]  (channel-major for coalesced atomics)
#define OFF_OUTG 2732032  // [72][4096]     (channel-major for coalesced atomics)
#define WS_FLOATS 3026944

__device__ __forceinline__ float fexp2(float x) {
#if __has_builtin(__builtin_amdgcn_exp2f)
  return __builtin_amdgcn_exp2f(x);
#else
  return exp2f(x);
#endif
}

__device__ __forceinline__ float dot4(float4 a, float4 b) {
  return a.x*b.x + a.y*b.y + a.z*b.z + a.w*b.w;
}

__device__ __forceinline__ float4 mix4(const float* __restrict__ W, const float* __restrict__ b,
                                       float x0, float x1, float x2, float x3, float sc)
{
  float4 r;
  r.x = (b[0] + W[0]*x0  + W[1]*x1  + W[2]*x2  + W[3]*x3)  * sc;
  r.y = (b[1] + W[4]*x0  + W[5]*x1  + W[6]*x2  + W[7]*x3)  * sc;
  r.z = (b[2] + W[8]*x0  + W[9]*x1  + W[10]*x2 + W[11]*x3) * sc;
  r.w = (b[3] + W[12]*x0 + W[13]*x1 + W[14]*x2 + W[15]*x3) * sc;
  return r;
}

// grid (16, 10) x 256. seg 0: chunk qkv. seg 1..9: global (mat m, out-ch group g of 24)
__global__ __launch_bounds__(256, 3) void k_qkv(const float* __restrict__ x,
    const float* __restrict__ Wq, const float* __restrict__ bq,
    const float* __restrict__ Wk, const float* __restrict__ bk,
    const float* __restrict__ Wv, const float* __restrict__ bv,
    const float* __restrict__ WqG, const float* __restrict__ bqG,
    const float* __restrict__ WkG, const float* __restrict__ bkG,
    const float* __restrict__ WvG, const float* __restrict__ bvG,
    float* __restrict__ ws)
{
  const int p = blockIdx.x * blockDim.x + threadIdx.x;
  const int seg = blockIdx.y;
  if (seg == 0) {
    float4* qd = reinterpret_cast<float4*>(ws + OFF_QC);
    float4* kd = reinterpret_cast<float4*>(ws + OFF_KC);
    float4* vd = reinterpret_cast<float4*>(ws + OFF_VC);
    for (int n = 0; n < NCHUNK; ++n) {
      const float x0 = x[(4*n+0)*NPIX + p];
      const float x1 = x[(4*n+1)*NPIX + p];
      const float x2 = x[(4*n+2)*NPIX + p];
      const float x3 = x[(4*n+3)*NPIX + p];
      float4 q = mix4(Wq + n*16, bq + n*4, x0, x1, x2, x3, SCALE_LOG2E);
      float4 k = mix4(Wk + n*16, bk + n*4, x0, x1, x2, x3, 1.0f);
      float4 v = mix4(Wv + n*16, bv + n*4, x0, x1, x2, x3, 1.0f);
      qd[n*NPIX + p] = q;
      kd[n*NPIX + p] = k;
      vd[n*NPIX + p] = v;
    }
  } else {
    const int m = (seg - 1) / 3;
    const int g = (seg - 1) % 3;
    const float* W = (m == 0) ? WqG : (m == 1) ? WkG : WvG;
    const float* b = (m == 0) ? bqG : (m == 1) ? bkG : bvG;
    float* dst = ws + ((m == 0) ? OFF_QG : (m == 1) ? OFF_KG : OFF_VG);
    float4 xv[18];
#pragma unroll
    for (int c = 0; c < 18; ++c) {
      float4 t;
      t.x = x[(4*c+0)*NPIX + p];
      t.y = x[(4*c+1)*NPIX + p];
      t.z = x[(4*c+2)*NPIX + p];
      t.w = x[(4*c+3)*NPIX + p];
      xv[c] = t;
    }
    const float sc = (m == 0) ? SCALE_LOG2E : 1.0f;
    const int ob = g * 24;
    for (int o = ob; o < ob + 24; ++o) {
      float acc = b[o];
      const float4* wrow = reinterpret_cast<const float4*>(W + o*NCH);
#pragma unroll
      for (int c = 0; c < 18; ++c) acc += dot4(wrow[c], xv[c]);
      dst[p*NCH + o] = acc * sc;
    }
  }
}

// chunk pass A: D_j = sum_i exp2(q_j . k_i).  grid (4, 18, 8) x 256, thread owns 4 j's
__global__ void k_chunkA(float* __restrict__ ws)
{
  const int n = blockIdx.y;
  const int jq = blockIdx.x * blockDim.x + threadIdx.x; // 0..1023
  const int j0 = jq * 4;
  const float4* qc = reinterpret_cast<const float4*>(ws + OFF_QC) + n*NPIX;
  const float4* kc = reinterpret_cast<const float4*>(ws + OFF_KC) + n*NPIX;
  float4 q0 = qc[j0+0], q1 = qc[j0+1], q2 = qc[j0+2], q3 = qc[j0+3];
  float d0 = 0.f, d1 = 0.f, d2 = 0.f, d3 = 0.f;
  const int ib = blockIdx.z * 512;
#pragma unroll 4
  for (int i = ib; i < ib + 512; ++i) {
    float4 k = kc[i];
    d0 += fexp2(dot4(q0, k));
    d1 += fexp2(dot4(q1, k));
    d2 += fexp2(dot4(q2, k));
    d3 += fexp2(dot4(q3, k));
  }
  float* Dc = ws + OFF_DC + n*NPIX;
  atomicAdd(&Dc[j0+0], d0);
  atomicAdd(&Dc[j0+1], d1);
  atomicAdd(&Dc[j0+2], d2);
  atomicAdd(&Dc[j0+3], d3);
}

// global pass A: DG_j = sum_i exp2(qG_j . kG_i).  grid (16, 1, 32) x 256
__global__ __launch_bounds__(256, 3) void k_gA(float* __restrict__ ws)
{
  const int j = blockIdx.x * blockDim.x + threadIdx.x;
  float4 q[18];
  const float4* qg = reinterpret_cast<const float4*>(ws + OFF_QG + j*NCH);
#pragma unroll
  for (int c = 0; c < 18; ++c) q[c] = qg[c];
  float d = 0.f;
  const int ib = blockIdx.z * 128;
  const float4* kg = reinterpret_cast<const float4*>(ws + OFF_KG);
#pragma unroll 2
  for (int i = ib; i < ib + 128; ++i) {
    const float4* kr = kg + i*18; // uniform across lanes -> broadcast loads
    float s = 0.f;
#pragma unroll
    for (int c = 0; c < 18; ++c) s += dot4(q[c], kr[c]);
    d += fexp2(s);
  }
  atomicAdd(ws + OFF_DG + j, d);
}

// w = v / D for both chunk and global.  grid (304) x 256
__global__ void k_wcomp(float* __restrict__ ws)
{
  const int t = blockIdx.x * blockDim.x + threadIdx.x;
  if (blockIdx.x < 288) {
    const int n = t >> 12, j = t & 4095;
    const float inv = 1.0f / ws[OFF_DC + n*NPIX + j];
    float4 v = reinterpret_cast<const float4*>(ws + OFF_VC)[n*NPIX + j];
    v.x *= inv; v.y *= inv; v.z *= inv; v.w *= inv;
    reinterpret_cast<float4*>(ws + OFF_WC)[n*NPIX + j] = v;
  } else {
    const int j = t - NCHUNK*NPIX; // 0..4095
    const float inv = 1.0f / ws[OFF_DG + j];
#pragma unroll
    for (int c = 0; c < NCH; c += 4) {
      float4 v = *reinterpret_cast<const float4*>(ws + OFF_VG + j*NCH + c);
      v.x *= inv; v.y *= inv; v.z *= inv; v.w *= inv;
      *reinterpret_cast<float4*>(ws + OFF_WG + j*NCH + c) = v;
    }
  }
}

// chunk pass B: outC[n][c][i] += sum_j w[c][j]*exp2(q_j.k_i).
// grid (4, 18, 8) x 256; thread handles i in {iq, iq+1024, iq+2048, iq+3072}
__global__ void k_chunkB(float* __restrict__ ws)
{
  const int n = blockIdx.y;
  const int iq = blockIdx.x * blockDim.x + threadIdx.x; // 0..1023
  const float4* kc = reinterpret_cast<const float4*>(ws + OFF_KC) + n*NPIX;
  const float4* qc = reinterpret_cast<const float4*>(ws + OFF_QC) + n*NPIX;
  const float4* wc = reinterpret_cast<const float4*>(ws + OFF_WC) + n*NPIX;
  float4 k0 = kc[iq], k1 = kc[iq+1024], k2 = kc[iq+2048], k3 = kc[iq+3072];
  float4 a0 = {0,0,0,0}, a1 = {0,0,0,0}, a2 = {0,0,0,0}, a3 = {0,0,0,0};
  const int jb = blockIdx.z * 512;
#pragma unroll 2
  for (int j = jb; j < jb + 512; ++j) {
    float4 q = qc[j];
    float4 w = wc[j];
    float e0 = fexp2(dot4(q, k0));
    float e1 = fexp2(dot4(q, k1));
    float e2 = fexp2(dot4(q, k2));
    float e3 = fexp2(dot4(q, k3));
    a0.x += e0*w.x; a0.y += e0*w.y; a0.z += e0*w.z; a0.w += e0*w.w;
    a1.x += e1*w.x; a1.y += e1*w.y; a1.z += e1*w.z; a1.w += e1*w.w;
    a2.x += e2*w.x; a2.y += e2*w.y; a2.z += e2*w.z; a2.w += e2*w.w;
    a3.x += e3*w.x; a3.y += e3*w.y; a3.z += e3*w.z; a3.w += e3*w.w;
  }
  float* oc = ws + OFF_OUTC + n*4*NPIX;
  atomicAdd(&oc[0*NPIX + iq       ], a0.x);
  atomicAdd(&oc[1*NPIX + iq       ], a0.y);
  atomicAdd(&oc[2*NPIX + iq       ], a0.z);
  atomicAdd(&oc[3*NPIX + iq       ], a0.w);
  atomicAdd(&oc[0*NPIX + iq + 1024], a1.x);
  atomicAdd(&oc[1*NPIX + iq + 1024], a1.y);
  atomicAdd(&oc[2*NPIX + iq + 1024], a1.z);
  atomicAdd(&oc[3*NPIX + iq + 1024], a1.w);
  atomicAdd(&oc[0*NPIX + iq + 2048], a2.x);
  atomicAdd(&oc[1*NPIX + iq + 2048], a2.y);
  atomicAdd(&oc[2*NPIX + iq + 2048], a2.z);
  atomicAdd(&oc[3*NPIX + iq + 2048], a2.w);
  atomicAdd(&oc[0*NPIX + iq + 3072], a3.x);
  atomicAdd(&oc[1*NPIX + iq + 3072], a3.y);
  atomicAdd(&oc[2*NPIX + iq + 3072], a3.z);
  atomicAdd(&oc[3*NPIX + iq + 3072], a3.w);
}

// global pass B: outG[c][i] += sum_j wG[j][c]*exp2(qG_j . kG_i).  grid (16, 1, 32) x 256
__global__ __launch_bounds__(256, 2) void k_gB(float* __restrict__ ws)
{
  const int i = blockIdx.x * blockDim.x + threadIdx.x;
  float4 k[18];
  const float4* kgr = reinterpret_cast<const float4*>(ws + OFF_KG + i*NCH);
#pragma unroll
  for (int c = 0; c < 18; ++c) k[c] = kgr[c];
  float4 acc[18];
#pragma unroll
  for (int c = 0; c < 18; ++c) acc[c] = float4{0,0,0,0};
  const int jb = blockIdx.z * 128;
  const float4* qg = reinterpret_cast<const float4*>(ws + OFF_QG);
  const float4* wg = reinterpret_cast<const float4*>(ws + OFF_WG);
#pragma unroll 2
  for (int j = jb; j < jb + 128; ++j) {
    const float4* qr = qg + j*18; // uniform across lanes
    const float4* wr = wg + j*18; // uniform across lanes
    float s = 0.f;
#pragma unroll
    for (int c = 0; c < 18; ++c) s += dot4(k[c], qr[c]);
    float e = fexp2(s);
#pragma unroll
    for (int c = 0; c < 18; ++c) {
      float4 w = wr[c];
      acc[c].x += e*w.x; acc[c].y += e*w.y; acc[c].z += e*w.z; acc[c].w += e*w.w;
    }
  }
  float* og = ws + OFF_OUTG;
#pragma unroll
  for (int c = 0; c < 18; ++c) {
    atomicAdd(&og[(4*c+0)*NPIX + i], acc[c].x);
    atomicAdd(&og[(4*c+1)*NPIX + i], acc[c].y);
    atomicAdd(&og[(4*c+2)*NPIX + i], acc[c].z);
    atomicAdd(&og[(4*c+3)*NPIX + i], acc[c].w);
  }
}

// pooled[n][p] = sum_r x[4n+r][p] * (outC[n][r][p] + outG[4n+r][p]).  grid (288) x 256
__global__ void k_final(const float* __restrict__ x, const float* __restrict__ ws,
                        float* __restrict__ out)
{
  const int t = blockIdx.x * blockDim.x + threadIdx.x;
  const int n = t >> 12, p = t & 4095;
  const float* oc = ws + OFF_OUTC + n*4*NPIX;
  const float* og = ws + OFF_OUTG + n*4*NPIX;
  float s = 0.f;
#pragma unroll
  for (int r = 0; r < 4; ++r) {
    s += x[(4*n+r)*NPIX + p] * (oc[r*NPIX + p] + og[r*NPIX + p]);
  }
  out[t] = s;
}

extern "C" void kernel_launch(void* const* d_in, const int* in_sizes, int n_in,
                              void* d_out, int out_size, void* d_ws, size_t ws_size,
                              hipStream_t stream)
{
  const float* x   = (const float*)d_in[0];
  const float* Wq  = (const float*)d_in[1];
  const float* bq  = (const float*)d_in[2];
  const float* Wk  = (const float*)d_in[3];
  const float* bk  = (const float*)d_in[4];
  const float* Wv  = (const float*)d_in[5];
  const float* bv  = (const float*)d_in[6];
  const float* WqG = (const float*)d_in[7];
  const float* bqG = (const float*)d_in[8];
  const float* WkG = (const float*)d_in[9];
  const float* bkG = (const float*)d_in[10];
  const float* WvG = (const float*)d_in[11];
  const float* bvG = (const float*)d_in[12];
  float* ws  = (float*)d_ws;
  float* out = (float*)d_out;

  if (ws_size < (size_t)WS_FLOATS * sizeof(float)) return; // need ~12.1 MB scratch

  // zero accumulators (Dc, DG, outC, outG are contiguous at the tail)
  hipMemsetAsync(ws + OFF_DC, 0, (size_t)(WS_FLOATS - OFF_DC) * sizeof(float), stream);

  hipLaunchKernelGGL(k_qkv, dim3(16, 10), dim3(256), 0, stream,
                     x, Wq, bq, Wk, bk, Wv, bv, WqG, bqG, WkG, bkG, WvG, bvG, ws);
  hipLaunchKernelGGL(k_chunkA, dim3(4, 18, 8), dim3(256), 0, stream, ws);
  hipLaunchKernelGGL(k_gA, dim3(16, 1, 32), dim3(256), 0, stream, ws);
  hipLaunchKernelGGL(k_wcomp, dim3(304), dim3(256), 0, stream, ws);
  hipLaunchKernelGGL(k_chunkB, dim3(4, 18, 8), dim3(256), 0, stream, ws);
  hipLaunchKernelGGL(k_gB, dim3(16, 1, 32), dim3(256), 0, stream, ws);
  hipLaunchKernelGGL(k_final, dim3(288), dim3(256), 0, stream, x, ws, out);
}

// Round 3
// 350.834 us; speedup vs baseline: 3.4873x; 2.2507x over previous
//
#include <hip/hip_runtime.h>

#define NPIX 4096
#define NCH 72
#define NCHUNK 18
#define KPAD 96

static constexpr float SCALE_LOG2E = 0.022542110013890054f; // (1/64)*log2(e)

// ws layout (float offsets)
#define OFF_QC 0          // [18][4096][4] f32 (scaled by SCALE_LOG2E)
#define OFF_KC 294912     // [18][4096][4] f32
#define OFF_VC 589824     // [18][4096][4] f32
#define OFF_WC 884736     // [18][4096][4] f32  v/D
#define OFF_VG 1179648    // [72][4096] f32 (c-major)
#define OFF_DC 1474560    // [18][4096] f32
#define OFF_DG 1548288    // [4096] f32
#define OFF_OUTC 1552384  // [18][4][4096] f32
#define OFF_OUTG 1847296  // [72][4096] f32
#define OFF_QB 2142208    // bf16 [4096][96]  (scaled, zero-padded 72..95)
#define OFF_KB 2338816    // bf16 [4096][96]  (zero-padded)
#define OFF_WB 2535424    // bf16 [80][4096]  (v/D, rows 72..79 zero)
#define WS_FLOATS 2699264

typedef __attribute__((ext_vector_type(8))) short short8v;
typedef __attribute__((ext_vector_type(4))) float f32x4;

__device__ __forceinline__ float fexp2(float x) {
#if __has_builtin(__builtin_amdgcn_exp2f)
  return __builtin_amdgcn_exp2f(x);
#else
  return exp2f(x);
#endif
}

__device__ __forceinline__ unsigned short bf16r(float f) {
  unsigned int u = __float_as_uint(f);
  u = (u + 0x7FFFu + ((u >> 16) & 1u)) >> 16;
  return (unsigned short)u;
}
__device__ __forceinline__ unsigned int bf16pair(float lo, float hi) {
  return (unsigned int)bf16r(lo) | ((unsigned int)bf16r(hi) << 16);
}

__device__ __forceinline__ f32x4 MFMA(short8v a, short8v b, f32x4 c) {
  return __builtin_amdgcn_mfma_f32_16x16x32_bf16(a, b, c, 0, 0, 0);
}

__device__ __forceinline__ float dot4(float4 a, float4 b) {
  return a.x*b.x + a.y*b.y + a.z*b.z + a.w*b.w;
}

__device__ __forceinline__ float4 mix4(const float* __restrict__ W, const float* __restrict__ b,
                                       float x0, float x1, float x2, float x3, float sc)
{
  float4 r;
  r.x = (b[0] + W[0]*x0  + W[1]*x1  + W[2]*x2  + W[3]*x3)  * sc;
  r.y = (b[1] + W[4]*x0  + W[5]*x1  + W[6]*x2  + W[7]*x3)  * sc;
  r.z = (b[2] + W[8]*x0  + W[9]*x1  + W[10]*x2 + W[11]*x3) * sc;
  r.w = (b[3] + W[12]*x0 + W[13]*x1 + W[14]*x2 + W[15]*x3) * sc;
  return r;
}

// grid (16, 10) x 256. seg 0: chunk qkv. seg 1..9: global (mat m, out-ch group g of 24)
__global__ __launch_bounds__(256, 3) void k_qkv(const float* __restrict__ x,
    const float* __restrict__ Wq, const float* __restrict__ bq,
    const float* __restrict__ Wk, const float* __restrict__ bk,
    const float* __restrict__ Wv, const float* __restrict__ bv,
    const float* __restrict__ WqG, const float* __restrict__ bqG,
    const float* __restrict__ WkG, const float* __restrict__ bkG,
    const float* __restrict__ WvG, const float* __restrict__ bvG,
    float* __restrict__ ws)
{
  const int p = blockIdx.x * blockDim.x + threadIdx.x;
  const int seg = blockIdx.y;
  if (seg == 0) {
    float4* qd = reinterpret_cast<float4*>(ws + OFF_QC);
    float4* kd = reinterpret_cast<float4*>(ws + OFF_KC);
    float4* vd = reinterpret_cast<float4*>(ws + OFF_VC);
    for (int n = 0; n < NCHUNK; ++n) {
      const float x0 = x[(4*n+0)*NPIX + p];
      const float x1 = x[(4*n+1)*NPIX + p];
      const float x2 = x[(4*n+2)*NPIX + p];
      const float x3 = x[(4*n+3)*NPIX + p];
      float4 q = mix4(Wq + n*16, bq + n*4, x0, x1, x2, x3, SCALE_LOG2E);
      float4 k = mix4(Wk + n*16, bk + n*4, x0, x1, x2, x3, 1.0f);
      float4 v = mix4(Wv + n*16, bv + n*4, x0, x1, x2, x3, 1.0f);
      qd[n*NPIX + p] = q;
      kd[n*NPIX + p] = k;
      vd[n*NPIX + p] = v;
    }
  } else {
    const int m = (seg - 1) / 3;
    const int g3 = (seg - 1) % 3;
    const float* W = (m == 0) ? WqG : (m == 1) ? WkG : WvG;
    const float* b = (m == 0) ? bqG : (m == 1) ? bkG : bvG;
    float4 xv[18];
#pragma unroll
    for (int c = 0; c < 18; ++c) {
      float4 t;
      t.x = x[(4*c+0)*NPIX + p];
      t.y = x[(4*c+1)*NPIX + p];
      t.z = x[(4*c+2)*NPIX + p];
      t.w = x[(4*c+3)*NPIX + p];
      xv[c] = t;
    }
    const int ob = g3 * 24;
    if (m == 2) {
      float* dst = ws + OFF_VG; // [72][4096]
      for (int o = ob; o < ob + 24; ++o) {
        float acc = b[o];
        const float4* wrow = reinterpret_cast<const float4*>(W + o*NCH);
#pragma unroll
        for (int c = 0; c < 18; ++c) acc += dot4(wrow[c], xv[c]);
        dst[o*NPIX + p] = acc;
      }
    } else {
      unsigned short* dst = reinterpret_cast<unsigned short*>(ws + ((m == 0) ? OFF_QB : OFF_KB));
      const float sc = (m == 0) ? SCALE_LOG2E : 1.0f;
      for (int o = ob; o < ob + 24; ++o) {
        float acc = b[o];
        const float4* wrow = reinterpret_cast<const float4*>(W + o*NCH);
#pragma unroll
        for (int c = 0; c < 18; ++c) acc += dot4(wrow[c], xv[c]);
        dst[p*KPAD + o] = bf16r(acc * sc);
      }
      if (g3 == 2) {
#pragma unroll
        for (int o = NCH; o < KPAD; ++o) dst[p*KPAD + o] = 0;
      }
    }
  }
}

// chunk pass A: D_j = sum_i exp2(q_j . k_i).  grid (4, 18, 8) x 256, thread owns 4 j's
__global__ void k_chunkA(float* __restrict__ ws)
{
  const int n = blockIdx.y;
  const int jq = blockIdx.x * blockDim.x + threadIdx.x; // 0..1023
  const int j0 = jq * 4;
  const float4* qc = reinterpret_cast<const float4*>(ws + OFF_QC) + n*NPIX;
  const float4* kc = reinterpret_cast<const float4*>(ws + OFF_KC) + n*NPIX;
  float4 q0 = qc[j0+0], q1 = qc[j0+1], q2 = qc[j0+2], q3 = qc[j0+3];
  float d0 = 0.f, d1 = 0.f, d2 = 0.f, d3 = 0.f;
  const int ib = blockIdx.z * 512;
#pragma unroll 4
  for (int i = ib; i < ib + 512; ++i) {
    float4 k = kc[i];
    d0 += fexp2(dot4(q0, k));
    d1 += fexp2(dot4(q1, k));
    d2 += fexp2(dot4(q2, k));
    d3 += fexp2(dot4(q3, k));
  }
  float* Dc = ws + OFF_DC + n*NPIX;
  atomicAdd(&Dc[j0+0], d0);
  atomicAdd(&Dc[j0+1], d1);
  atomicAdd(&Dc[j0+2], d2);
  atomicAdd(&Dc[j0+3], d3);
}

// global pass A (MFMA): D[j] = sum_i exp2(S[j][i]).  grid (64, 8) x 256
// block: 64 j (16 per wave) x 512 i segment
__global__ __launch_bounds__(256, 2) void k_mA(float* __restrict__ ws)
{
  const unsigned short* QB = reinterpret_cast<const unsigned short*>(ws + OFF_QB);
  const unsigned short* KB = reinterpret_cast<const unsigned short*>(ws + OFF_KB);
  const int w = threadIdx.x >> 6, l = threadIdx.x & 63;
  const int g = l >> 4, li = l & 15;
  const int j0 = blockIdx.x * 64 + w * 16;
  const int i0 = blockIdx.y * 512;
  short8v qa[3];
#pragma unroll
  for (int kk = 0; kk < 3; ++kk)
    qa[kk] = *reinterpret_cast<const short8v*>(QB + (j0 + li)*KPAD + kk*32 + 8*g);
  float ds0 = 0.f, ds1 = 0.f, ds2 = 0.f, ds3 = 0.f;
  for (int t = 0; t < 32; ++t) {
    const int i = i0 + t*16;
    f32x4 acc = {0.f, 0.f, 0.f, 0.f};
#pragma unroll
    for (int kk = 0; kk < 3; ++kk) {
      short8v kb = *reinterpret_cast<const short8v*>(KB + (i + li)*KPAD + kk*32 + 8*g);
      acc = MFMA(qa[kk], kb, acc);
    }
    ds0 += fexp2(acc[0]);
    ds1 += fexp2(acc[1]);
    ds2 += fexp2(acc[2]);
    ds3 += fexp2(acc[3]);
  }
#pragma unroll
  for (int m = 1; m < 16; m <<= 1) {
    ds0 += __shfl_xor(ds0, m, 64);
    ds1 += __shfl_xor(ds1, m, 64);
    ds2 += __shfl_xor(ds2, m, 64);
    ds3 += __shfl_xor(ds3, m, 64);
  }
  if (li == 0) {
    float* D = ws + OFF_DG;
    atomicAdd(&D[j0 + 4*g + 0], ds0);
    atomicAdd(&D[j0 + 4*g + 1], ds1);
    atomicAdd(&D[j0 + 4*g + 2], ds2);
    atomicAdd(&D[j0 + 4*g + 3], ds3);
  }
}

// w = v / D for both chunk and global.  grid (304) x 256
__global__ void k_wcomp(float* __restrict__ ws)
{
  const int t = blockIdx.x * blockDim.x + threadIdx.x;
  if (blockIdx.x < 288) {
    const int n = t >> 12, j = t & 4095;
    const float inv = 1.0f / ws[OFF_DC + n*NPIX + j];
    float4 v = reinterpret_cast<const float4*>(ws + OFF_VC)[n*NPIX + j];
    v.x *= inv; v.y *= inv; v.z *= inv; v.w *= inv;
    reinterpret_cast<float4*>(ws + OFF_WC)[n*NPIX + j] = v;
  } else {
    const int j = t - NCHUNK*NPIX; // 0..4095
    const float inv = 1.0f / ws[OFF_DG + j];
    unsigned short* WB = reinterpret_cast<unsigned short*>(ws + OFF_WB);
    const float* VG = ws + OFF_VG;
#pragma unroll
    for (int c = 0; c < NCH; ++c)
      WB[c*NPIX + j] = bf16r(VG[c*NPIX + j] * inv);
#pragma unroll
    for (int c = NCH; c < 80; ++c) WB[c*NPIX + j] = 0;
  }
}

// chunk pass B: outC[n][c][i] += sum_j w[c][j]*exp2(q_j.k_i).
// grid (4, 18, 8) x 256; thread handles i in {iq, iq+1024, iq+2048, iq+3072}
__global__ void k_chunkB(float* __restrict__ ws)
{
  const int n = blockIdx.y;
  const int iq = blockIdx.x * blockDim.x + threadIdx.x; // 0..1023
  const float4* kc = reinterpret_cast<const float4*>(ws + OFF_KC) + n*NPIX;
  const float4* qc = reinterpret_cast<const float4*>(ws + OFF_QC) + n*NPIX;
  const float4* wc = reinterpret_cast<const float4*>(ws + OFF_WC) + n*NPIX;
  float4 k0 = kc[iq], k1 = kc[iq+1024], k2 = kc[iq+2048], k3 = kc[iq+3072];
  float4 a0 = {0,0,0,0}, a1 = {0,0,0,0}, a2 = {0,0,0,0}, a3 = {0,0,0,0};
  const int jb = blockIdx.z * 512;
#pragma unroll 2
  for (int j = jb; j < jb + 512; ++j) {
    float4 q = qc[j];
    float4 w = wc[j];
    float e0 = fexp2(dot4(q, k0));
    float e1 = fexp2(dot4(q, k1));
    float e2 = fexp2(dot4(q, k2));
    float e3 = fexp2(dot4(q, k3));
    a0.x += e0*w.x; a0.y += e0*w.y; a0.z += e0*w.z; a0.w += e0*w.w;
    a1.x += e1*w.x; a1.y += e1*w.y; a1.z += e1*w.z; a1.w += e1*w.w;
    a2.x += e2*w.x; a2.y += e2*w.y; a2.z += e2*w.z; a2.w += e2*w.w;
    a3.x += e3*w.x; a3.y += e3*w.y; a3.z += e3*w.z; a3.w += e3*w.w;
  }
  float* oc = ws + OFF_OUTC + n*4*NPIX;
  atomicAdd(&oc[0*NPIX + iq       ], a0.x);
  atomicAdd(&oc[1*NPIX + iq       ], a0.y);
  atomicAdd(&oc[2*NPIX + iq       ], a0.z);
  atomicAdd(&oc[3*NPIX + iq       ], a0.w);
  atomicAdd(&oc[0*NPIX + iq + 1024], a1.x);
  atomicAdd(&oc[1*NPIX + iq + 1024], a1.y);
  atomicAdd(&oc[2*NPIX + iq + 1024], a1.z);
  atomicAdd(&oc[3*NPIX + iq + 1024], a1.w);
  atomicAdd(&oc[0*NPIX + iq + 2048], a2.x);
  atomicAdd(&oc[1*NPIX + iq + 2048], a2.y);
  atomicAdd(&oc[2*NPIX + iq + 2048], a2.z);
  atomicAdd(&oc[3*NPIX + iq + 2048], a2.w);
  atomicAdd(&oc[0*NPIX + iq + 3072], a3.x);
  atomicAdd(&oc[1*NPIX + iq + 3072], a3.y);
  atomicAdd(&oc[2*NPIX + iq + 3072], a3.z);
  atomicAdd(&oc[3*NPIX + iq + 3072], a3.w);
}

// global pass B (MFMA): OUT[c][i] += sum_j WB[c][j]*exp2(S[j][i]).  grid (64, 8) x 256
// block: 64 i (16 per wave) x 512 j segment; per-wave-private LDS E-tile
__global__ __launch_bounds__(256, 2) void k_mB(float* __restrict__ ws)
{
  __shared__ unsigned int E_dw[4][16][36];
  const unsigned short* QB = reinterpret_cast<const unsigned short*>(ws + OFF_QB);
  const unsigned short* KB = reinterpret_cast<const unsigned short*>(ws + OFF_KB);
  const unsigned short* WB = reinterpret_cast<const unsigned short*>(ws + OFF_WB);
  const int w = threadIdx.x >> 6, l = threadIdx.x & 63;
  const int g = l >> 4, li = l & 15;
  const int iw = blockIdx.x * 64 + w * 16;
  const int jbase = blockIdx.y * 512;
  short8v kb[3];
#pragma unroll
  for (int kk = 0; kk < 3; ++kk)
    kb[kk] = *reinterpret_cast<const short8v*>(KB + (iw + li)*KPAD + kk*32 + 8*g);
  f32x4 accW[5];
#pragma unroll
  for (int m = 0; m < 5; ++m) accW[m] = (f32x4){0.f, 0.f, 0.f, 0.f};
  unsigned int (*Em)[36] = E_dw[w];
  for (int t = 0; t < 16; ++t) {
    const int jb = jbase + t*32;
    // first GEMM: E tile 32j x 16i (two 16x16 m-tiles)
#pragma unroll
    for (int m = 0; m < 2; ++m) {
      f32x4 acc = {0.f, 0.f, 0.f, 0.f};
#pragma unroll
      for (int kk = 0; kk < 3; ++kk) {
        short8v qa = *reinterpret_cast<const short8v*>(QB + (jb + m*16 + li)*KPAD + kk*32 + 8*g);
        acc = MFMA(qa, kb[kk], acc);
      }
      // lane holds rows j_local = m*16 + 4g + {0..3}, col i = iw + li
      Em[li][m*8 + 2*g    ] = bf16pair(fexp2(acc[0]), fexp2(acc[1]));
      Em[li][m*8 + 2*g + 1] = bf16pair(fexp2(acc[2]), fexp2(acc[3]));
    }
    // same-wave DS ops execute in order: re-read as B-fragment (k = j_local = 8g..8g+7)
    short8v eb = *reinterpret_cast<const short8v*>(&Em[li][4*g]);
    // second GEMM: accW[m] += WB-tile (16c x 32j) * E (32j x 16i)
#pragma unroll
    for (int m = 0; m < 5; ++m) {
      short8v wa = *reinterpret_cast<const short8v*>(WB + (m*16 + li)*NPIX + jb + 8*g);
      accW[m] = MFMA(wa, eb, accW[m]);
    }
  }
  float* OG = ws + OFF_OUTG;
#pragma unroll
  for (int m = 0; m < 5; ++m) {
#pragma unroll
    for (int r = 0; r < 4; ++r) {
      const int c = m*16 + 4*g + r;
      if (c < NCH) atomicAdd(&OG[c*NPIX + iw + li], accW[m][r]);
    }
  }
}

// pooled[n][p] = sum_r x[4n+r][p] * (outC[n][r][p] + outG[4n+r][p]).  grid (288) x 256
__global__ void k_final(const float* __restrict__ x, const float* __restrict__ ws,
                        float* __restrict__ out)
{
  const int t = blockIdx.x * blockDim.x + threadIdx.x;
  const int n = t >> 12, p = t & 4095;
  const float* oc = ws + OFF_OUTC + n*4*NPIX;
  const float* og = ws + OFF_OUTG + n*4*NPIX;
  float s = 0.f;
#pragma unroll
  for (int r = 0; r < 4; ++r) {
    s += x[(4*n+r)*NPIX + p] * (oc[r*NPIX + p] + og[r*NPIX + p]);
  }
  out[t] = s;
}

extern "C" void kernel_launch(void* const* d_in, const int* in_sizes, int n_in,
                              void* d_out, int out_size, void* d_ws, size_t ws_size,
                              hipStream_t stream)
{
  const float* x   = (const float*)d_in[0];
  const float* Wq  = (const float*)d_in[1];
  const float* bq  = (const float*)d_in[2];
  const float* Wk  = (const float*)d_in[3];
  const float* bk  = (const float*)d_in[4];
  const float* Wv  = (const float*)d_in[5];
  const float* bv  = (const float*)d_in[6];
  const float* WqG = (const float*)d_in[7];
  const float* bqG = (const float*)d_in[8];
  const float* WkG = (const float*)d_in[9];
  const float* bkG = (const float*)d_in[10];
  const float* WvG = (const float*)d_in[11];
  const float* bvG = (const float*)d_in[12];
  float* ws  = (float*)d_ws;
  float* out = (float*)d_out;

  if (ws_size < (size_t)WS_FLOATS * sizeof(float)) return; // need ~10.8 MB scratch

  // zero accumulators (DC, DG, OUTC, OUTG contiguous)
  hipMemsetAsync(ws + OFF_DC, 0, (size_t)(OFF_QB - OFF_DC) * sizeof(float), stream);

  hipLaunchKernelGGL(k_qkv, dim3(16, 10), dim3(256), 0, stream,
                     x, Wq, bq, Wk, bk, Wv, bv, WqG, bqG, WkG, bkG, WvG, bvG, ws);
  hipLaunchKernelGGL(k_chunkA, dim3(4, 18, 8), dim3(256), 0, stream, ws);
  hipLaunchKernelGGL(k_mA, dim3(64, 8), dim3(256), 0, stream, ws);
  hipLaunchKernelGGL(k_wcomp, dim3(304), dim3(256), 0, stream, ws);
  hipLaunchKernelGGL(k_chunkB, dim3(4, 18, 8), dim3(256), 0, stream, ws);
  hipLaunchKernelGGL(k_mB, dim3(64, 8), dim3(256), 0, stream, ws);
  hipLaunchKernelGGL(k_final, dim3(288), dim3(256), 0, stream, x, ws, out);
}

// Round 4
// 288.019 us; speedup vs baseline: 4.2479x; 1.2181x over previous
//
#include <hip/hip_runtime.h>

#define NPIX 4096
#define NCH 72
#define NCHUNK 18
#define KPAD 96

static constexpr float SCALE_LOG2E = 0.022542110013890054f; // (1/64)*log2(e)

// ws layout (float offsets)
#define OFF_QC 0          // [18][4096][4] f32 (scaled by SCALE_LOG2E)
#define OFF_KC 294912     // [18][4096][4] f32
#define OFF_VC 589824     // [18][4096][4] f32
#define OFF_WC 884736     // [18][4096][4] f32  v/D
#define OFF_VG 1179648    // [72][4096] f32 (c-major)
#define OFF_DC 1474560    // [18][4096] f32
#define OFF_DG 1548288    // [4096] f32
#define OFF_OUTC 1552384  // [18][4][4096] f32
#define OFF_OUTG 1847296  // [72][4096] f32
#define OFF_QB 2142208    // bf16 [4096][96]  (scaled, zero-padded 72..95)
#define OFF_KB 2338816    // bf16 [4096][96]  (zero-padded)
#define OFF_WB 2535424    // bf16 [80][4096]  (v/D, rows 72..79 zero)
#define WS_FLOATS 2699264

typedef __attribute__((ext_vector_type(8))) short short8v;
typedef __attribute__((ext_vector_type(4))) float f32x4;

__device__ __forceinline__ float fexp2(float x) {
#if __has_builtin(__builtin_amdgcn_exp2f)
  return __builtin_amdgcn_exp2f(x);
#else
  return exp2f(x);
#endif
}

__device__ __forceinline__ unsigned short bf16r(float f) {
  unsigned int u = __float_as_uint(f);
  u = (u + 0x7FFFu + ((u >> 16) & 1u)) >> 16;
  return (unsigned short)u;
}
__device__ __forceinline__ unsigned int bf16pair(float lo, float hi) {
  return (unsigned int)bf16r(lo) | ((unsigned int)bf16r(hi) << 16);
}

__device__ __forceinline__ f32x4 MFMA(short8v a, short8v b, f32x4 c) {
  return __builtin_amdgcn_mfma_f32_16x16x32_bf16(a, b, c, 0, 0, 0);
}

__device__ __forceinline__ float dot4(float4 a, float4 b) {
  return a.x*b.x + a.y*b.y + a.z*b.z + a.w*b.w;
}

__device__ __forceinline__ float4 mix4(const float* __restrict__ W, const float* __restrict__ b,
                                       float x0, float x1, float x2, float x3, float sc)
{
  float4 r;
  r.x = (b[0] + W[0]*x0  + W[1]*x1  + W[2]*x2  + W[3]*x3)  * sc;
  r.y = (b[1] + W[4]*x0  + W[5]*x1  + W[6]*x2  + W[7]*x3)  * sc;
  r.z = (b[2] + W[8]*x0  + W[9]*x1  + W[10]*x2 + W[11]*x3) * sc;
  r.w = (b[3] + W[12]*x0 + W[13]*x1 + W[14]*x2 + W[15]*x3) * sc;
  return r;
}

// grid (16, 15) x 256. seg 0..5: chunk qkv (3 chunks each). seg 6..14: global (mat m, group g)
__global__ __launch_bounds__(256, 3) void k_qkv(const float* __restrict__ x,
    const float* __restrict__ Wq, const float* __restrict__ bq,
    const float* __restrict__ Wk, const float* __restrict__ bk,
    const float* __restrict__ Wv, const float* __restrict__ bv,
    const float* __restrict__ WqG, const float* __restrict__ bqG,
    const float* __restrict__ WkG, const float* __restrict__ bkG,
    const float* __restrict__ WvG, const float* __restrict__ bvG,
    float* __restrict__ ws)
{
  const int p = blockIdx.x * blockDim.x + threadIdx.x;
  const int seg = blockIdx.y;
  if (seg < 6) {
    float4* qd = reinterpret_cast<float4*>(ws + OFF_QC);
    float4* kd = reinterpret_cast<float4*>(ws + OFF_KC);
    float4* vd = reinterpret_cast<float4*>(ws + OFF_VC);
    const int n0 = seg * 3;
#pragma unroll
    for (int dn = 0; dn < 3; ++dn) {
      const int n = n0 + dn;
      const float x0 = x[(4*n+0)*NPIX + p];
      const float x1 = x[(4*n+1)*NPIX + p];
      const float x2 = x[(4*n+2)*NPIX + p];
      const float x3 = x[(4*n+3)*NPIX + p];
      float4 q = mix4(Wq + n*16, bq + n*4, x0, x1, x2, x3, SCALE_LOG2E);
      float4 k = mix4(Wk + n*16, bk + n*4, x0, x1, x2, x3, 1.0f);
      float4 v = mix4(Wv + n*16, bv + n*4, x0, x1, x2, x3, 1.0f);
      qd[n*NPIX + p] = q;
      kd[n*NPIX + p] = k;
      vd[n*NPIX + p] = v;
    }
  } else {
    const int m = (seg - 6) / 3;
    const int g3 = (seg - 6) % 3;
    const float* W = (m == 0) ? WqG : (m == 1) ? WkG : WvG;
    const float* b = (m == 0) ? bqG : (m == 1) ? bkG : bvG;
    float4 xv[18];
#pragma unroll
    for (int c = 0; c < 18; ++c) {
      float4 t;
      t.x = x[(4*c+0)*NPIX + p];
      t.y = x[(4*c+1)*NPIX + p];
      t.z = x[(4*c+2)*NPIX + p];
      t.w = x[(4*c+3)*NPIX + p];
      xv[c] = t;
    }
    const int ob = g3 * 24;
    if (m == 2) {
      float* dst = ws + OFF_VG; // [72][4096]
      for (int o = ob; o < ob + 24; ++o) {
        float acc = b[o];
        const float4* wrow = reinterpret_cast<const float4*>(W + o*NCH);
#pragma unroll
        for (int c = 0; c < 18; ++c) acc += dot4(wrow[c], xv[c]);
        dst[o*NPIX + p] = acc;
      }
    } else {
      unsigned short* dst = reinterpret_cast<unsigned short*>(ws + ((m == 0) ? OFF_QB : OFF_KB));
      const float sc = (m == 0) ? SCALE_LOG2E : 1.0f;
      for (int o = ob; o < ob + 24; ++o) {
        float acc = b[o];
        const float4* wrow = reinterpret_cast<const float4*>(W + o*NCH);
#pragma unroll
        for (int c = 0; c < 18; ++c) acc += dot4(wrow[c], xv[c]);
        dst[p*KPAD + o] = bf16r(acc * sc);
      }
      if (g3 == 2) {
#pragma unroll
        for (int o = NCH; o < KPAD; ++o) dst[p*KPAD + o] = 0;
      }
    }
  }
}

// chunk pass A: D_j = sum_i exp2(q_j . k_i).
// grid (2, 18, 16) x 256; thread owns 8 j's (jb + s*256 + tid); i-tile of 256 staged in LDS
__global__ __launch_bounds__(256, 4) void k_chunkA(float* __restrict__ ws)
{
  __shared__ float4 Kt[256];
  const int n = blockIdx.y;
  const int tid = threadIdx.x;
  const int jb = blockIdx.x * 2048;
  const int i0 = blockIdx.z * 256;
  const float4* qc = reinterpret_cast<const float4*>(ws + OFF_QC) + n*NPIX;
  const float4* kc = reinterpret_cast<const float4*>(ws + OFF_KC) + n*NPIX;
  Kt[tid] = kc[i0 + tid];
  float4 q[8];
  float d[8];
#pragma unroll
  for (int s = 0; s < 8; ++s) { q[s] = qc[jb + s*256 + tid]; d[s] = 0.f; }
  __syncthreads();
#pragma unroll 4
  for (int i = 0; i < 256; ++i) {
    float4 k = Kt[i];
#pragma unroll
    for (int s = 0; s < 8; ++s) d[s] += fexp2(dot4(q[s], k));
  }
  float* Dc = ws + OFF_DC + n*NPIX;
#pragma unroll
  for (int s = 0; s < 8; ++s) atomicAdd(&Dc[jb + s*256 + tid], d[s]);
}

// global pass A (MFMA): D[j] = sum_i exp2(S[j][i]).  grid (64, 8) x 256
__global__ __launch_bounds__(256, 2) void k_mA(float* __restrict__ ws)
{
  const unsigned short* QB = reinterpret_cast<const unsigned short*>(ws + OFF_QB);
  const unsigned short* KB = reinterpret_cast<const unsigned short*>(ws + OFF_KB);
  const int w = threadIdx.x >> 6, l = threadIdx.x & 63;
  const int g = l >> 4, li = l & 15;
  const int j0 = blockIdx.x * 64 + w * 16;
  const int i0 = blockIdx.y * 512;
  short8v qa[3];
#pragma unroll
  for (int kk = 0; kk < 3; ++kk)
    qa[kk] = *reinterpret_cast<const short8v*>(QB + (j0 + li)*KPAD + kk*32 + 8*g);
  float ds0 = 0.f, ds1 = 0.f, ds2 = 0.f, ds3 = 0.f;
  for (int t = 0; t < 32; ++t) {
    const int i = i0 + t*16;
    f32x4 acc = {0.f, 0.f, 0.f, 0.f};
#pragma unroll
    for (int kk = 0; kk < 3; ++kk) {
      short8v kb = *reinterpret_cast<const short8v*>(KB + (i + li)*KPAD + kk*32 + 8*g);
      acc = MFMA(qa[kk], kb, acc);
    }
    ds0 += fexp2(acc[0]);
    ds1 += fexp2(acc[1]);
    ds2 += fexp2(acc[2]);
    ds3 += fexp2(acc[3]);
  }
#pragma unroll
  for (int m = 1; m < 16; m <<= 1) {
    ds0 += __shfl_xor(ds0, m, 64);
    ds1 += __shfl_xor(ds1, m, 64);
    ds2 += __shfl_xor(ds2, m, 64);
    ds3 += __shfl_xor(ds3, m, 64);
  }
  if (li == 0) {
    float* D = ws + OFF_DG;
    atomicAdd(&D[j0 + 4*g + 0], ds0);
    atomicAdd(&D[j0 + 4*g + 1], ds1);
    atomicAdd(&D[j0 + 4*g + 2], ds2);
    atomicAdd(&D[j0 + 4*g + 3], ds3);
  }
}

// w = v / D for both chunk and global.  grid (304) x 256
__global__ void k_wcomp(float* __restrict__ ws)
{
  const int t = blockIdx.x * blockDim.x + threadIdx.x;
  if (blockIdx.x < 288) {
    const int n = t >> 12, j = t & 4095;
    const float inv = 1.0f / ws[OFF_DC + n*NPIX + j];
    float4 v = reinterpret_cast<const float4*>(ws + OFF_VC)[n*NPIX + j];
    v.x *= inv; v.y *= inv; v.z *= inv; v.w *= inv;
    reinterpret_cast<float4*>(ws + OFF_WC)[n*NPIX + j] = v;
  } else {
    const int j = t - NCHUNK*NPIX; // 0..4095
    const float inv = 1.0f / ws[OFF_DG + j];
    unsigned short* WB = reinterpret_cast<unsigned short*>(ws + OFF_WB);
    const float* VG = ws + OFF_VG;
#pragma unroll
    for (int c = 0; c < NCH; ++c)
      WB[c*NPIX + j] = bf16r(VG[c*NPIX + j] * inv);
#pragma unroll
    for (int c = NCH; c < 80; ++c) WB[c*NPIX + j] = 0;
  }
}

// chunk pass B: outC[n][c][i] += sum_j w[c][j]*exp2(q_j.k_i).
// grid (2, 18, 16) x 256; thread owns 8 i's (ib + s*256 + tid); j-tile of 256 staged in LDS
__global__ __launch_bounds__(256, 4) void k_chunkB(float* __restrict__ ws)
{
  __shared__ float4 Qt[256];
  __shared__ float4 Wt[256];
  const int n = blockIdx.y;
  const int tid = threadIdx.x;
  const int ib = blockIdx.x * 2048;
  const int j0 = blockIdx.z * 256;
  const float4* kc = reinterpret_cast<const float4*>(ws + OFF_KC) + n*NPIX;
  const float4* qc = reinterpret_cast<const float4*>(ws + OFF_QC) + n*NPIX;
  const float4* wc = reinterpret_cast<const float4*>(ws + OFF_WC) + n*NPIX;
  Qt[tid] = qc[j0 + tid];
  Wt[tid] = wc[j0 + tid];
  float4 k[8];
  float4 a[8];
#pragma unroll
  for (int s = 0; s < 8; ++s) { k[s] = kc[ib + s*256 + tid]; a[s] = float4{0,0,0,0}; }
  __syncthreads();
#pragma unroll 2
  for (int j = 0; j < 256; ++j) {
    float4 q = Qt[j];
    float4 w = Wt[j];
#pragma unroll
    for (int s = 0; s < 8; ++s) {
      float e = fexp2(dot4(q, k[s]));
      a[s].x += e*w.x; a[s].y += e*w.y; a[s].z += e*w.z; a[s].w += e*w.w;
    }
  }
  float* oc = ws + OFF_OUTC + n*4*NPIX;
#pragma unroll
  for (int s = 0; s < 8; ++s) {
    const int i = ib + s*256 + tid;
    atomicAdd(&oc[0*NPIX + i], a[s].x);
    atomicAdd(&oc[1*NPIX + i], a[s].y);
    atomicAdd(&oc[2*NPIX + i], a[s].z);
    atomicAdd(&oc[3*NPIX + i], a[s].w);
  }
}

// global pass B (MFMA): OUT[c][i] += sum_j WB[c][j]*exp2(S[j][i]).  grid (64, 8) x 256
__global__ __launch_bounds__(256, 2) void k_mB(float* __restrict__ ws)
{
  __shared__ unsigned int E_dw[4][16][36];
  const unsigned short* QB = reinterpret_cast<const unsigned short*>(ws + OFF_QB);
  const unsigned short* KB = reinterpret_cast<const unsigned short*>(ws + OFF_KB);
  const unsigned short* WB = reinterpret_cast<const unsigned short*>(ws + OFF_WB);
  const int w = threadIdx.x >> 6, l = threadIdx.x & 63;
  const int g = l >> 4, li = l & 15;
  const int iw = blockIdx.x * 64 + w * 16;
  const int jbase = blockIdx.y * 512;
  short8v kb[3];
#pragma unroll
  for (int kk = 0; kk < 3; ++kk)
    kb[kk] = *reinterpret_cast<const short8v*>(KB + (iw + li)*KPAD + kk*32 + 8*g);
  f32x4 accW[5];
#pragma unroll
  for (int m = 0; m < 5; ++m) accW[m] = (f32x4){0.f, 0.f, 0.f, 0.f};
  unsigned int (*Em)[36] = E_dw[w];
  for (int t = 0; t < 16; ++t) {
    const int jb = jbase + t*32;
#pragma unroll
    for (int m = 0; m < 2; ++m) {
      f32x4 acc = {0.f, 0.f, 0.f, 0.f};
#pragma unroll
      for (int kk = 0; kk < 3; ++kk) {
        short8v qa = *reinterpret_cast<const short8v*>(QB + (jb + m*16 + li)*KPAD + kk*32 + 8*g);
        acc = MFMA(qa, kb[kk], acc);
      }
      Em[li][m*8 + 2*g    ] = bf16pair(fexp2(acc[0]), fexp2(acc[1]));
      Em[li][m*8 + 2*g + 1] = bf16pair(fexp2(acc[2]), fexp2(acc[3]));
    }
    short8v eb = *reinterpret_cast<const short8v*>(&Em[li][4*g]);
#pragma unroll
    for (int m = 0; m < 5; ++m) {
      short8v wa = *reinterpret_cast<const short8v*>(WB + (m*16 + li)*NPIX + jb + 8*g);
      accW[m] = MFMA(wa, eb, accW[m]);
    }
  }
  float* OG = ws + OFF_OUTG;
#pragma unroll
  for (int m = 0; m < 5; ++m) {
#pragma unroll
    for (int r = 0; r < 4; ++r) {
      const int c = m*16 + 4*g + r;
      if (c < NCH) atomicAdd(&OG[c*NPIX + iw + li], accW[m][r]);
    }
  }
}

// pooled[n][p] = sum_r x[4n+r][p] * (outC[n][r][p] + outG[4n+r][p]).  grid (288) x 256
__global__ void k_final(const float* __restrict__ x, const float* __restrict__ ws,
                        float* __restrict__ out)
{
  const int t = blockIdx.x * blockDim.x + threadIdx.x;
  const int n = t >> 12, p = t & 4095;
  const float* oc = ws + OFF_OUTC + n*4*NPIX;
  const float* og = ws + OFF_OUTG + n*4*NPIX;
  float s = 0.f;
#pragma unroll
  for (int r = 0; r < 4; ++r) {
    s += x[(4*n+r)*NPIX + p] * (oc[r*NPIX + p] + og[r*NPIX + p]);
  }
  out[t] = s;
}

extern "C" void kernel_launch(void* const* d_in, const int* in_sizes, int n_in,
                              void* d_out, int out_size, void* d_ws, size_t ws_size,
                              hipStream_t stream)
{
  const float* x   = (const float*)d_in[0];
  const float* Wq  = (const float*)d_in[1];
  const float* bq  = (const float*)d_in[2];
  const float* Wk  = (const float*)d_in[3];
  const float* bk  = (const float*)d_in[4];
  const float* Wv  = (const float*)d_in[5];
  const float* bv  = (const float*)d_in[6];
  const float* WqG = (const float*)d_in[7];
  const float* bqG = (const float*)d_in[8];
  const float* WkG = (const float*)d_in[9];
  const float* bkG = (const float*)d_in[10];
  const float* WvG = (const float*)d_in[11];
  const float* bvG = (const float*)d_in[12];
  float* ws  = (float*)d_ws;
  float* out = (float*)d_out;

  if (ws_size < (size_t)WS_FLOATS * sizeof(float)) return; // need ~10.8 MB scratch

  // zero accumulators (DC, DG, OUTC, OUTG contiguous)
  hipMemsetAsync(ws + OFF_DC, 0, (size_t)(OFF_QB - OFF_DC) * sizeof(float), stream);

  hipLaunchKernelGGL(k_qkv, dim3(16, 15), dim3(256), 0, stream,
                     x, Wq, bq, Wk, bk, Wv, bv, WqG, bqG, WkG, bkG, WvG, bvG, ws);
  hipLaunchKernelGGL(k_chunkA, dim3(2, 18, 16), dim3(256), 0, stream, ws);
  hipLaunchKernelGGL(k_mA, dim3(64, 8), dim3(256), 0, stream, ws);
  hipLaunchKernelGGL(k_wcomp, dim3(304), dim3(256), 0, stream, ws);
  hipLaunchKernelGGL(k_chunkB, dim3(2, 18, 16), dim3(256), 0, stream, ws);
  hipLaunchKernelGGL(k_mB, dim3(64, 8), dim3(256), 0, stream, ws);
  hipLaunchKernelGGL(k_final, dim3(288), dim3(256), 0, stream, x, ws, out);
}

// Round 5
// 213.608 us; speedup vs baseline: 5.7276x; 1.3484x over previous
//
#include <hip/hip_runtime.h>

#define NPIX 4096
#define NCH 72
#define NCHUNK 18
#define KPAD 96

static constexpr float SCALE_LOG2E = 0.022542110013890054f; // (1/64)*log2(e)

// ws layout (float offsets)
#define OFF_VC 0          // [18][4096][4] f32 chunk v
#define OFF_VG 294912     // [72][4096] f32 global v (c-major)
#define OFF_DC 589824     // [18][4096] f32 (direct-stored by k_cA)
#define OFF_DG 663552     // [4096] f32 (atomics; memset)
#define OFF_OUTG 667648   // [72][4096] f32 (atomics; memset, contiguous with DG)
#define OFF_OUTC 962560   // [18][4][4096] f32 (direct-stored by k_cB)
#define OFF_QB 1257472    // bf16 [4096][96] global q (scaled, zero-padded 72..95)
#define OFF_KB 1454080    // bf16 [4096][96] global k (zero-padded)
#define OFF_WB 1650688    // bf16 [80][4096] global v/D (rows 72..79 zero)
#define OFF_QCB 1814528   // bf16 [18][4096][8] chunk q (scaled, elems 4..7 zero)
#define OFF_KCB 2109440   // bf16 [18][4096][8] chunk k (elems 4..7 zero)
#define OFF_WCB 2404352   // bf16 [18][4][4096] chunk v/D
#define WS_FLOATS 2551808

typedef __attribute__((ext_vector_type(8))) short short8v;
typedef __attribute__((ext_vector_type(4))) float f32x4;

__device__ __forceinline__ float fexp2(float x) {
#if __has_builtin(__builtin_amdgcn_exp2f)
  return __builtin_amdgcn_exp2f(x);
#else
  return exp2f(x);
#endif
}

__device__ __forceinline__ unsigned short bf16r(float f) {
  unsigned int u = __float_as_uint(f);
  u = (u + 0x7FFFu + ((u >> 16) & 1u)) >> 16;
  return (unsigned short)u;
}
__device__ __forceinline__ unsigned int bf16pair(float lo, float hi) {
  return (unsigned int)bf16r(lo) | ((unsigned int)bf16r(hi) << 16);
}

__device__ __forceinline__ f32x4 MFMA(short8v a, short8v b, f32x4 c) {
  return __builtin_amdgcn_mfma_f32_16x16x32_bf16(a, b, c, 0, 0, 0);
}

__device__ __forceinline__ float dot4(float4 a, float4 b) {
  return a.x*b.x + a.y*b.y + a.z*b.z + a.w*b.w;
}

__device__ __forceinline__ float4 mix4(const float* __restrict__ W, const float* __restrict__ b,
                                       float x0, float x1, float x2, float x3, float sc)
{
  float4 r;
  r.x = (b[0] + W[0]*x0  + W[1]*x1  + W[2]*x2  + W[3]*x3)  * sc;
  r.y = (b[1] + W[4]*x0  + W[5]*x1  + W[6]*x2  + W[7]*x3)  * sc;
  r.z = (b[2] + W[8]*x0  + W[9]*x1  + W[10]*x2 + W[11]*x3) * sc;
  r.w = (b[3] + W[12]*x0 + W[13]*x1 + W[14]*x2 + W[15]*x3) * sc;
  return r;
}

// grid (16, 15) x 256. seg 0..5: chunk qkv (3 chunks each). seg 6..14: global (mat m, group g)
__global__ __launch_bounds__(256, 3) void k_qkv(const float* __restrict__ x,
    const float* __restrict__ Wq, const float* __restrict__ bq,
    const float* __restrict__ Wk, const float* __restrict__ bk,
    const float* __restrict__ Wv, const float* __restrict__ bv,
    const float* __restrict__ WqG, const float* __restrict__ bqG,
    const float* __restrict__ WkG, const float* __restrict__ bkG,
    const float* __restrict__ WvG, const float* __restrict__ bvG,
    float* __restrict__ ws)
{
  const int p = blockIdx.x * blockDim.x + threadIdx.x;
  const int seg = blockIdx.y;
  if (seg < 6) {
    unsigned short* qcb = reinterpret_cast<unsigned short*>(ws + OFF_QCB);
    unsigned short* kcb = reinterpret_cast<unsigned short*>(ws + OFF_KCB);
    float4* vd = reinterpret_cast<float4*>(ws + OFF_VC);
    const int n0 = seg * 3;
#pragma unroll
    for (int dn = 0; dn < 3; ++dn) {
      const int n = n0 + dn;
      const float x0 = x[(4*n+0)*NPIX + p];
      const float x1 = x[(4*n+1)*NPIX + p];
      const float x2 = x[(4*n+2)*NPIX + p];
      const float x3 = x[(4*n+3)*NPIX + p];
      float4 q = mix4(Wq + n*16, bq + n*4, x0, x1, x2, x3, SCALE_LOG2E);
      float4 k = mix4(Wk + n*16, bk + n*4, x0, x1, x2, x3, 1.0f);
      float4 v = mix4(Wv + n*16, bv + n*4, x0, x1, x2, x3, 1.0f);
      short8v qs = { (short)bf16r(q.x), (short)bf16r(q.y), (short)bf16r(q.z), (short)bf16r(q.w), 0,0,0,0 };
      short8v ks = { (short)bf16r(k.x), (short)bf16r(k.y), (short)bf16r(k.z), (short)bf16r(k.w), 0,0,0,0 };
      *reinterpret_cast<short8v*>(qcb + ((size_t)n*NPIX + p)*8) = qs;
      *reinterpret_cast<short8v*>(kcb + ((size_t)n*NPIX + p)*8) = ks;
      vd[n*NPIX + p] = v;
    }
  } else {
    const int m = (seg - 6) / 3;
    const int g3 = (seg - 6) % 3;
    const float* W = (m == 0) ? WqG : (m == 1) ? WkG : WvG;
    const float* b = (m == 0) ? bqG : (m == 1) ? bkG : bvG;
    float4 xv[18];
#pragma unroll
    for (int c = 0; c < 18; ++c) {
      float4 t;
      t.x = x[(4*c+0)*NPIX + p];
      t.y = x[(4*c+1)*NPIX + p];
      t.z = x[(4*c+2)*NPIX + p];
      t.w = x[(4*c+3)*NPIX + p];
      xv[c] = t;
    }
    const int ob = g3 * 24;
    if (m == 2) {
      float* dst = ws + OFF_VG; // [72][4096]
      for (int o = ob; o < ob + 24; ++o) {
        float acc = b[o];
        const float4* wrow = reinterpret_cast<const float4*>(W + o*NCH);
#pragma unroll
        for (int c = 0; c < 18; ++c) acc += dot4(wrow[c], xv[c]);
        dst[o*NPIX + p] = acc;
      }
    } else {
      unsigned short* dst = reinterpret_cast<unsigned short*>(ws + ((m == 0) ? OFF_QB : OFF_KB));
      const float sc = (m == 0) ? SCALE_LOG2E : 1.0f;
      for (int o = ob; o < ob + 24; ++o) {
        float acc = b[o];
        const float4* wrow = reinterpret_cast<const float4*>(W + o*NCH);
#pragma unroll
        for (int c = 0; c < 18; ++c) acc += dot4(wrow[c], xv[c]);
        dst[p*KPAD + o] = bf16r(acc * sc);
      }
      if (g3 == 2) {
#pragma unroll
        for (int o = NCH; o < KPAD; ++o) dst[p*KPAD + o] = 0;
      }
    }
  }
}

// chunk pass A (MFMA): DC[n][j] = sum_i exp2(q_j.k_i).  grid (64, 18) x 256
// wave owns 16 j's, loops all 4096 i.  A-frag zeroed for g>=1 => K=32 acts as K=4.
__global__ __launch_bounds__(256, 4) void k_cA(float* __restrict__ ws)
{
  const unsigned short* QCB = reinterpret_cast<const unsigned short*>(ws + OFF_QCB);
  const unsigned short* KCB = reinterpret_cast<const unsigned short*>(ws + OFF_KCB);
  const int w = threadIdx.x >> 6, l = threadIdx.x & 63;
  const int g = l >> 4, li = l & 15;
  const int n = blockIdx.y;
  const int j0 = blockIdx.x * 64 + w * 16;
  short8v qz = {0,0,0,0,0,0,0,0};
  short8v qa = qz;
  if (g == 0) qa = *reinterpret_cast<const short8v*>(QCB + ((size_t)n*NPIX + j0 + li)*8);
  const unsigned short* kbase = KCB + (size_t)n*NPIX*8 + li*8;
  float d0 = 0.f, d1 = 0.f, d2 = 0.f, d3 = 0.f;
#pragma unroll 4
  for (int t = 0; t < 256; ++t) {
    short8v kb = *reinterpret_cast<const short8v*>(kbase + t*128); // i = t*16 + li
    f32x4 z = {0.f,0.f,0.f,0.f};
    f32x4 acc = MFMA(qa, kb, z);
    d0 += fexp2(acc[0]);
    d1 += fexp2(acc[1]);
    d2 += fexp2(acc[2]);
    d3 += fexp2(acc[3]);
  }
#pragma unroll
  for (int m = 1; m < 16; m <<= 1) {
    d0 += __shfl_xor(d0, m, 64);
    d1 += __shfl_xor(d1, m, 64);
    d2 += __shfl_xor(d2, m, 64);
    d3 += __shfl_xor(d3, m, 64);
  }
  if (li == 0) {
    float* Dc = ws + OFF_DC + n*NPIX;
    Dc[j0 + 4*g + 0] = d0;
    Dc[j0 + 4*g + 1] = d1;
    Dc[j0 + 4*g + 2] = d2;
    Dc[j0 + 4*g + 3] = d3;
  }
}

// global pass A (MFMA): D[j] = sum_i exp2(S[j][i]).  grid (64, 8) x 256
__global__ __launch_bounds__(256, 2) void k_mA(float* __restrict__ ws)
{
  const unsigned short* QB = reinterpret_cast<const unsigned short*>(ws + OFF_QB);
  const unsigned short* KB = reinterpret_cast<const unsigned short*>(ws + OFF_KB);
  const int w = threadIdx.x >> 6, l = threadIdx.x & 63;
  const int g = l >> 4, li = l & 15;
  const int j0 = blockIdx.x * 64 + w * 16;
  const int i0 = blockIdx.y * 512;
  short8v qa[3];
#pragma unroll
  for (int kk = 0; kk < 3; ++kk)
    qa[kk] = *reinterpret_cast<const short8v*>(QB + (j0 + li)*KPAD + kk*32 + 8*g);
  float ds0 = 0.f, ds1 = 0.f, ds2 = 0.f, ds3 = 0.f;
  for (int t = 0; t < 32; ++t) {
    const int i = i0 + t*16;
    f32x4 acc = {0.f, 0.f, 0.f, 0.f};
#pragma unroll
    for (int kk = 0; kk < 3; ++kk) {
      short8v kb = *reinterpret_cast<const short8v*>(KB + (i + li)*KPAD + kk*32 + 8*g);
      acc = MFMA(qa[kk], kb, acc);
    }
    ds0 += fexp2(acc[0]);
    ds1 += fexp2(acc[1]);
    ds2 += fexp2(acc[2]);
    ds3 += fexp2(acc[3]);
  }
#pragma unroll
  for (int m = 1; m < 16; m <<= 1) {
    ds0 += __shfl_xor(ds0, m, 64);
    ds1 += __shfl_xor(ds1, m, 64);
    ds2 += __shfl_xor(ds2, m, 64);
    ds3 += __shfl_xor(ds3, m, 64);
  }
  if (li == 0) {
    float* D = ws + OFF_DG;
    atomicAdd(&D[j0 + 4*g + 0], ds0);
    atomicAdd(&D[j0 + 4*g + 1], ds1);
    atomicAdd(&D[j0 + 4*g + 2], ds2);
    atomicAdd(&D[j0 + 4*g + 3], ds3);
  }
}

// w = v / D for both chunk and global.  grid (304) x 256
__global__ void k_wcomp(float* __restrict__ ws)
{
  const int t = blockIdx.x * blockDim.x + threadIdx.x;
  if (blockIdx.x < 288) {
    const int n = t >> 12, j = t & 4095;
    const float inv = 1.0f / ws[OFF_DC + n*NPIX + j];
    float4 v = reinterpret_cast<const float4*>(ws + OFF_VC)[n*NPIX + j];
    unsigned short* WCB = reinterpret_cast<unsigned short*>(ws + OFF_WCB);
    WCB[((size_t)n*4 + 0)*NPIX + j] = bf16r(v.x * inv);
    WCB[((size_t)n*4 + 1)*NPIX + j] = bf16r(v.y * inv);
    WCB[((size_t)n*4 + 2)*NPIX + j] = bf16r(v.z * inv);
    WCB[((size_t)n*4 + 3)*NPIX + j] = bf16r(v.w * inv);
  } else {
    const int j = t - NCHUNK*NPIX; // 0..4095
    const float inv = 1.0f / ws[OFF_DG + j];
    unsigned short* WB = reinterpret_cast<unsigned short*>(ws + OFF_WB);
    const float* VG = ws + OFF_VG;
#pragma unroll
    for (int c = 0; c < NCH; ++c)
      WB[c*NPIX + j] = bf16r(VG[c*NPIX + j] * inv);
#pragma unroll
    for (int c = NCH; c < 80; ++c) WB[c*NPIX + j] = 0;
  }
}

// chunk pass B (MFMA): OUTC[n][c][i] = sum_j WCB[n][c][j]*exp2(q_j.k_i).  grid (64, 18) x 256
// wave owns 16 i's, loops all 4096 j in 32-steps. B-frag (kb) zeroed for g>=1.
__global__ __launch_bounds__(256, 4) void k_cB(float* __restrict__ ws)
{
  __shared__ unsigned int E_dw[4][16][36];
  const unsigned short* QCB = reinterpret_cast<const unsigned short*>(ws + OFF_QCB);
  const unsigned short* KCB = reinterpret_cast<const unsigned short*>(ws + OFF_KCB);
  const unsigned short* WCB = reinterpret_cast<const unsigned short*>(ws + OFF_WCB);
  const int w = threadIdx.x >> 6, l = threadIdx.x & 63;
  const int g = l >> 4, li = l & 15;
  const int n = blockIdx.y;
  const int i0 = blockIdx.x * 64 + w * 16;
  short8v kz = {0,0,0,0,0,0,0,0};
  short8v kb = kz;
  if (g == 0) kb = *reinterpret_cast<const short8v*>(KCB + ((size_t)n*NPIX + i0 + li)*8);
  const unsigned short* qbase = QCB + (size_t)n*NPIX*8 + li*8;
  const unsigned short* wbase = WCB + ((size_t)n*4 + (li < 4 ? li : 3))*NPIX + 8*g;
  f32x4 accW = {0.f, 0.f, 0.f, 0.f};
  unsigned int (*Em)[36] = E_dw[w];
#pragma unroll 2
  for (int t = 0; t < 128; ++t) {
    const int jb = t*32;
    short8v qa0 = *reinterpret_cast<const short8v*>(qbase + (size_t)jb*8);        // rows jb..jb+15
    short8v qa1 = *reinterpret_cast<const short8v*>(qbase + (size_t)(jb+16)*8);   // rows jb+16..jb+31
    short8v wa  = *reinterpret_cast<const short8v*>(wbase + jb);                  // W[c][jb+8g..+7]
    f32x4 z = {0.f,0.f,0.f,0.f};
    f32x4 s0 = MFMA(qa0, kb, z);
    f32x4 s1 = MFMA(qa1, kb, z);
    Em[li][2*g    ] = bf16pair(fexp2(s0[0]), fexp2(s0[1]));
    Em[li][2*g + 1] = bf16pair(fexp2(s0[2]), fexp2(s0[3]));
    Em[li][8 + 2*g    ] = bf16pair(fexp2(s1[0]), fexp2(s1[1]));
    Em[li][8 + 2*g + 1] = bf16pair(fexp2(s1[2]), fexp2(s1[3]));
    short8v eb = *reinterpret_cast<const short8v*>(&Em[li][4*g]); // E[jb+8g..+7][i0+li]
    accW = MFMA(wa, eb, accW);
  }
  if (g == 0) {
    float* oc = ws + OFF_OUTC + (size_t)n*4*NPIX + i0 + li;
    oc[0*NPIX] = accW[0];
    oc[1*NPIX] = accW[1];
    oc[2*NPIX] = accW[2];
    oc[3*NPIX] = accW[3];
  }
}

// global pass B (MFMA): OUT[c][i] += sum_j WB[c][j]*exp2(S[j][i]).  grid (64, 8) x 256
__global__ __launch_bounds__(256, 2) void k_mB(float* __restrict__ ws)
{
  __shared__ unsigned int E_dw[4][16][36];
  const unsigned short* QB = reinterpret_cast<const unsigned short*>(ws + OFF_QB);
  const unsigned short* KB = reinterpret_cast<const unsigned short*>(ws + OFF_KB);
  const unsigned short* WB = reinterpret_cast<const unsigned short*>(ws + OFF_WB);
  const int w = threadIdx.x >> 6, l = threadIdx.x & 63;
  const int g = l >> 4, li = l & 15;
  const int iw = blockIdx.x * 64 + w * 16;
  const int jbase = blockIdx.y * 512;
  short8v kb[3];
#pragma unroll
  for (int kk = 0; kk < 3; ++kk)
    kb[kk] = *reinterpret_cast<const short8v*>(KB + (iw + li)*KPAD + kk*32 + 8*g);
  f32x4 accW[5];
#pragma unroll
  for (int m = 0; m < 5; ++m) accW[m] = (f32x4){0.f, 0.f, 0.f, 0.f};
  unsigned int (*Em)[36] = E_dw[w];
  for (int t = 0; t < 16; ++t) {
    const int jb = jbase + t*32;
#pragma unroll
    for (int m = 0; m < 2; ++m) {
      f32x4 acc = {0.f, 0.f, 0.f, 0.f};
#pragma unroll
      for (int kk = 0; kk < 3; ++kk) {
        short8v qa = *reinterpret_cast<const short8v*>(QB + (jb + m*16 + li)*KPAD + kk*32 + 8*g);
        acc = MFMA(qa, kb[kk], acc);
      }
      Em[li][m*8 + 2*g    ] = bf16pair(fexp2(acc[0]), fexp2(acc[1]));
      Em[li][m*8 + 2*g + 1] = bf16pair(fexp2(acc[2]), fexp2(acc[3]));
    }
    short8v eb = *reinterpret_cast<const short8v*>(&Em[li][4*g]);
#pragma unroll
    for (int m = 0; m < 5; ++m) {
      short8v wa = *reinterpret_cast<const short8v*>(WB + (m*16 + li)*NPIX + jb + 8*g);
      accW[m] = MFMA(wa, eb, accW[m]);
    }
  }
  float* OG = ws + OFF_OUTG;
#pragma unroll
  for (int m = 0; m < 5; ++m) {
#pragma unroll
    for (int r = 0; r < 4; ++r) {
      const int c = m*16 + 4*g + r;
      if (c < NCH) atomicAdd(&OG[c*NPIX + iw + li], accW[m][r]);
    }
  }
}

// pooled[n][p] = sum_r x[4n+r][p] * (outC[n][r][p] + outG[4n+r][p]).  grid (288) x 256
__global__ void k_final(const float* __restrict__ x, const float* __restrict__ ws,
                        float* __restrict__ out)
{
  const int t = blockIdx.x * blockDim.x + threadIdx.x;
  const int n = t >> 12, p = t & 4095;
  const float* oc = ws + OFF_OUTC + (size_t)n*4*NPIX;
  const float* og = ws + OFF_OUTG + (size_t)n*4*NPIX;
  float s = 0.f;
#pragma unroll
  for (int r = 0; r < 4; ++r) {
    s += x[(4*n+r)*NPIX + p] * (oc[r*NPIX + p] + og[r*NPIX + p]);
  }
  out[t] = s;
}

extern "C" void kernel_launch(void* const* d_in, const int* in_sizes, int n_in,
                              void* d_out, int out_size, void* d_ws, size_t ws_size,
                              hipStream_t stream)
{
  const float* x   = (const float*)d_in[0];
  const float* Wq  = (const float*)d_in[1];
  const float* bq  = (const float*)d_in[2];
  const float* Wk  = (const float*)d_in[3];
  const float* bk  = (const float*)d_in[4];
  const float* Wv  = (const float*)d_in[5];
  const float* bv  = (const float*)d_in[6];
  const float* WqG = (const float*)d_in[7];
  const float* bqG = (const float*)d_in[8];
  const float* WkG = (const float*)d_in[9];
  const float* bkG = (const float*)d_in[10];
  const float* WvG = (const float*)d_in[11];
  const float* bvG = (const float*)d_in[12];
  float* ws  = (float*)d_ws;
  float* out = (float*)d_out;

  if (ws_size < (size_t)WS_FLOATS * sizeof(float)) return; // need ~10.2 MB scratch

  // zero only the atomic accumulators: DG + OUTG (contiguous)
  hipMemsetAsync(ws + OFF_DG, 0, (size_t)(4096 + NCH*NPIX) * sizeof(float), stream);

  hipLaunchKernelGGL(k_qkv, dim3(16, 15), dim3(256), 0, stream,
                     x, Wq, bq, Wk, bk, Wv, bv, WqG, bqG, WkG, bkG, WvG, bvG, ws);
  hipLaunchKernelGGL(k_cA, dim3(64, 18), dim3(256), 0, stream, ws);
  hipLaunchKernelGGL(k_mA, dim3(64, 8), dim3(256), 0, stream, ws);
  hipLaunchKernelGGL(k_wcomp, dim3(304), dim3(256), 0, stream, ws);
  hipLaunchKernelGGL(k_cB, dim3(64, 18), dim3(256), 0, stream, ws);
  hipLaunchKernelGGL(k_mB, dim3(64, 8), dim3(256), 0, stream, ws);
  hipLaunchKernelGGL(k_final, dim3(288), dim3(256), 0, stream, x, ws, out);
}

// Round 6
// 204.741 us; speedup vs baseline: 5.9757x; 1.0433x over previous
//
#include <hip/hip_runtime.h>

#define NPIX 4096
#define NCH 72
#define NCHUNK 18
#define KPAD 96

static constexpr float SCALE_LOG2E = 0.022542110013890054f; // (1/64)*log2(e)

// ws layout (float offsets)
#define OFF_VC 0          // [18][4096][4] f32 chunk v; becomes v/D in-place after k_wcomp
#define OFF_VG 294912     // [72][4096] f32 global v (c-major)
#define OFF_DC 589824     // [18][4096] f32 (direct-stored by k_cA)
#define OFF_DG 663552     // [4096] f32 (atomics; memset)
#define OFF_OUTG 667648   // [72][4096] f32 (atomics; memset, contiguous with DG)
#define OFF_OUTC 962560   // [18][4096][4] f32 (direct-stored by k_cB, pixel-major float4)
#define OFF_QB 1257472    // bf16 [4096][96] global q (scaled, zero-padded 72..95)
#define OFF_KB 1454080    // bf16 [4096][96] global k (zero-padded)
#define OFF_WB 1650688    // bf16 [80][4096] global v/D (rows 72..79 zero)
#define OFF_QCB 1814528   // bf16 [18][4096][8] chunk q (scaled, elems 4..7 zero)
#define OFF_KCB 2109440   // bf16 [18][4096][8] chunk k (elems 4..7 zero)
#define WS_FLOATS 2404352

typedef __attribute__((ext_vector_type(8))) short short8v;
typedef __attribute__((ext_vector_type(4))) float f32x4;

__device__ __forceinline__ float fexp2(float x) {
#if __has_builtin(__builtin_amdgcn_exp2f)
  return __builtin_amdgcn_exp2f(x);
#else
  return exp2f(x);
#endif
}

__device__ __forceinline__ unsigned short bf16r(float f) {
  unsigned int u = __float_as_uint(f);
  u = (u + 0x7FFFu + ((u >> 16) & 1u)) >> 16;
  return (unsigned short)u;
}
__device__ __forceinline__ unsigned int bf16pair(float lo, float hi) {
  return (unsigned int)bf16r(lo) | ((unsigned int)bf16r(hi) << 16);
}

__device__ __forceinline__ f32x4 MFMA(short8v a, short8v b, f32x4 c) {
  return __builtin_amdgcn_mfma_f32_16x16x32_bf16(a, b, c, 0, 0, 0);
}

__device__ __forceinline__ float dot4(float4 a, float4 b) {
  return a.x*b.x + a.y*b.y + a.z*b.z + a.w*b.w;
}

__device__ __forceinline__ float4 mix4(const float* __restrict__ W, const float* __restrict__ b,
                                       float x0, float x1, float x2, float x3, float sc)
{
  float4 r;
  r.x = (b[0] + W[0]*x0  + W[1]*x1  + W[2]*x2  + W[3]*x3)  * sc;
  r.y = (b[1] + W[4]*x0  + W[5]*x1  + W[6]*x2  + W[7]*x3)  * sc;
  r.z = (b[2] + W[8]*x0  + W[9]*x1  + W[10]*x2 + W[11]*x3) * sc;
  r.w = (b[3] + W[12]*x0 + W[13]*x1 + W[14]*x2 + W[15]*x3) * sc;
  return r;
}

// grid (16, 24) x 256. seg 0..5: chunk qkv (3 chunks each). seg 6..23: global (mat m, group of 12)
__global__ __launch_bounds__(256, 3) void k_qkv(const float* __restrict__ x,
    const float* __restrict__ Wq, const float* __restrict__ bq,
    const float* __restrict__ Wk, const float* __restrict__ bk,
    const float* __restrict__ Wv, const float* __restrict__ bv,
    const float* __restrict__ WqG, const float* __restrict__ bqG,
    const float* __restrict__ WkG, const float* __restrict__ bkG,
    const float* __restrict__ WvG, const float* __restrict__ bvG,
    float* __restrict__ ws)
{
  const int p = blockIdx.x * blockDim.x + threadIdx.x;
  const int seg = blockIdx.y;
  if (seg < 6) {
    unsigned short* qcb = reinterpret_cast<unsigned short*>(ws + OFF_QCB);
    unsigned short* kcb = reinterpret_cast<unsigned short*>(ws + OFF_KCB);
    float4* vd = reinterpret_cast<float4*>(ws + OFF_VC);
    const int n0 = seg * 3;
#pragma unroll
    for (int dn = 0; dn < 3; ++dn) {
      const int n = n0 + dn;
      const float x0 = x[(4*n+0)*NPIX + p];
      const float x1 = x[(4*n+1)*NPIX + p];
      const float x2 = x[(4*n+2)*NPIX + p];
      const float x3 = x[(4*n+3)*NPIX + p];
      float4 q = mix4(Wq + n*16, bq + n*4, x0, x1, x2, x3, SCALE_LOG2E);
      float4 k = mix4(Wk + n*16, bk + n*4, x0, x1, x2, x3, 1.0f);
      float4 v = mix4(Wv + n*16, bv + n*4, x0, x1, x2, x3, 1.0f);
      short8v qs = { (short)bf16r(q.x), (short)bf16r(q.y), (short)bf16r(q.z), (short)bf16r(q.w), 0,0,0,0 };
      short8v ks = { (short)bf16r(k.x), (short)bf16r(k.y), (short)bf16r(k.z), (short)bf16r(k.w), 0,0,0,0 };
      *reinterpret_cast<short8v*>(qcb + ((size_t)n*NPIX + p)*8) = qs;
      *reinterpret_cast<short8v*>(kcb + ((size_t)n*NPIX + p)*8) = ks;
      vd[n*NPIX + p] = v;
    }
  } else {
    const int m = (seg - 6) / 6;
    const int g6 = (seg - 6) % 6;
    const float* W = (m == 0) ? WqG : (m == 1) ? WkG : WvG;
    const float* b = (m == 0) ? bqG : (m == 1) ? bkG : bvG;
    float4 xv[18];
#pragma unroll
    for (int c = 0; c < 18; ++c) {
      float4 t;
      t.x = x[(4*c+0)*NPIX + p];
      t.y = x[(4*c+1)*NPIX + p];
      t.z = x[(4*c+2)*NPIX + p];
      t.w = x[(4*c+3)*NPIX + p];
      xv[c] = t;
    }
    const int ob = g6 * 12;
    if (m == 2) {
      float* dst = ws + OFF_VG; // [72][4096]
      for (int o = ob; o < ob + 12; ++o) {
        float acc = b[o];
        const float4* wrow = reinterpret_cast<const float4*>(W + o*NCH);
#pragma unroll
        for (int c = 0; c < 18; ++c) acc += dot4(wrow[c], xv[c]);
        dst[o*NPIX + p] = acc;
      }
    } else {
      unsigned short* dst = reinterpret_cast<unsigned short*>(ws + ((m == 0) ? OFF_QB : OFF_KB));
      const float sc = (m == 0) ? SCALE_LOG2E : 1.0f;
      for (int o = ob; o < ob + 12; ++o) {
        float acc = b[o];
        const float4* wrow = reinterpret_cast<const float4*>(W + o*NCH);
#pragma unroll
        for (int c = 0; c < 18; ++c) acc += dot4(wrow[c], xv[c]);
        dst[p*KPAD + o] = bf16r(acc * sc);
      }
      if (g6 == 5) {
#pragma unroll
        for (int o = NCH; o < KPAD; ++o) dst[p*KPAD + o] = 0;
      }
    }
  }
}

// chunk pass A (MFMA): DC[n][j] = sum_i exp2(q_j.k_i).  grid (64, 18) x 256
// wave owns 16 j's, loops all 4096 i.  A-frag zeroed for g>=1 => K=32 acts as K=4.
__global__ __launch_bounds__(256, 4) void k_cA(float* __restrict__ ws)
{
  const unsigned short* QCB = reinterpret_cast<const unsigned short*>(ws + OFF_QCB);
  const unsigned short* KCB = reinterpret_cast<const unsigned short*>(ws + OFF_KCB);
  const int w = threadIdx.x >> 6, l = threadIdx.x & 63;
  const int g = l >> 4, li = l & 15;
  const int n = blockIdx.y;
  const int j0 = blockIdx.x * 64 + w * 16;
  short8v qz = {0,0,0,0,0,0,0,0};
  short8v qa = qz;
  if (g == 0) qa = *reinterpret_cast<const short8v*>(QCB + ((size_t)n*NPIX + j0 + li)*8);
  const unsigned short* kbase = KCB + (size_t)n*NPIX*8 + li*8;
  float d0 = 0.f, d1 = 0.f, d2 = 0.f, d3 = 0.f;
#pragma unroll 4
  for (int t = 0; t < 256; ++t) {
    short8v kb = *reinterpret_cast<const short8v*>(kbase + t*128); // i = t*16 + li
    f32x4 z = {0.f,0.f,0.f,0.f};
    f32x4 acc = MFMA(qa, kb, z);
    d0 += fexp2(acc[0]);
    d1 += fexp2(acc[1]);
    d2 += fexp2(acc[2]);
    d3 += fexp2(acc[3]);
  }
#pragma unroll
  for (int m = 1; m < 16; m <<= 1) {
    d0 += __shfl_xor(d0, m, 64);
    d1 += __shfl_xor(d1, m, 64);
    d2 += __shfl_xor(d2, m, 64);
    d3 += __shfl_xor(d3, m, 64);
  }
  if (li == 0) {
    float* Dc = ws + OFF_DC + n*NPIX;
    Dc[j0 + 4*g + 0] = d0;
    Dc[j0 + 4*g + 1] = d1;
    Dc[j0 + 4*g + 2] = d2;
    Dc[j0 + 4*g + 3] = d3;
  }
}

// global pass A (MFMA): D[j] = sum_i exp2(S[j][i]).  grid (64, 8) x 256
__global__ __launch_bounds__(256, 2) void k_mA(float* __restrict__ ws)
{
  const unsigned short* QB = reinterpret_cast<const unsigned short*>(ws + OFF_QB);
  const unsigned short* KB = reinterpret_cast<const unsigned short*>(ws + OFF_KB);
  const int w = threadIdx.x >> 6, l = threadIdx.x & 63;
  const int g = l >> 4, li = l & 15;
  const int j0 = blockIdx.x * 64 + w * 16;
  const int i0 = blockIdx.y * 512;
  short8v qa[3];
#pragma unroll
  for (int kk = 0; kk < 3; ++kk)
    qa[kk] = *reinterpret_cast<const short8v*>(QB + (j0 + li)*KPAD + kk*32 + 8*g);
  float ds0 = 0.f, ds1 = 0.f, ds2 = 0.f, ds3 = 0.f;
  for (int t = 0; t < 32; ++t) {
    const int i = i0 + t*16;
    f32x4 acc = {0.f, 0.f, 0.f, 0.f};
#pragma unroll
    for (int kk = 0; kk < 3; ++kk) {
      short8v kb = *reinterpret_cast<const short8v*>(KB + (i + li)*KPAD + kk*32 + 8*g);
      acc = MFMA(qa[kk], kb, acc);
    }
    ds0 += fexp2(acc[0]);
    ds1 += fexp2(acc[1]);
    ds2 += fexp2(acc[2]);
    ds3 += fexp2(acc[3]);
  }
#pragma unroll
  for (int m = 1; m < 16; m <<= 1) {
    ds0 += __shfl_xor(ds0, m, 64);
    ds1 += __shfl_xor(ds1, m, 64);
    ds2 += __shfl_xor(ds2, m, 64);
    ds3 += __shfl_xor(ds3, m, 64);
  }
  if (li == 0) {
    float* D = ws + OFF_DG;
    atomicAdd(&D[j0 + 4*g + 0], ds0);
    atomicAdd(&D[j0 + 4*g + 1], ds1);
    atomicAdd(&D[j0 + 4*g + 2], ds2);
    atomicAdd(&D[j0 + 4*g + 3], ds3);
  }
}

// w = v / D.  chunk: in-place VC /= D.  global: WB = bf16(VG/D).  grid (304) x 256
__global__ void k_wcomp(float* __restrict__ ws)
{
  const int t = blockIdx.x * blockDim.x + threadIdx.x;
  if (blockIdx.x < 288) {
    const int n = t >> 12, j = t & 4095;
    const float inv = 1.0f / ws[OFF_DC + n*NPIX + j];
    float4* vc = reinterpret_cast<float4*>(ws + OFF_VC) + ((size_t)n*NPIX + j);
    float4 v = *vc;
    v.x *= inv; v.y *= inv; v.z *= inv; v.w *= inv;
    *vc = v;
  } else {
    const int j = t - NCHUNK*NPIX; // 0..4095
    const float inv = 1.0f / ws[OFF_DG + j];
    unsigned short* WB = reinterpret_cast<unsigned short*>(ws + OFF_WB);
    const float* VG = ws + OFF_VG;
#pragma unroll
    for (int c = 0; c < NCH; ++c)
      WB[c*NPIX + j] = bf16r(VG[c*NPIX + j] * inv);
#pragma unroll
    for (int c = NCH; c < 80; ++c) WB[c*NPIX + j] = 0;
  }
}

// chunk pass B (MFMA, transpose-free): OUTC[n][i][c] = sum_j w[j][c]*exp2(q_j.k_i).
// grid (64, 18) x 256.  Wave owns 16 i (A = K-frag, fixed); streams j.
// Output lane (g,li) reg r = S[j=jb+li][i=i0+4g+r]; PV update stays in registers:
// acc[r] += w4(j=jb+li) * e_r.  Reduce over li (shfl_xor 1,2,4,8) at the end.
__global__ __launch_bounds__(256, 4) void k_cB(float* __restrict__ ws)
{
  const unsigned short* QCB = reinterpret_cast<const unsigned short*>(ws + OFF_QCB);
  const unsigned short* KCB = reinterpret_cast<const unsigned short*>(ws + OFF_KCB);
  const int w = threadIdx.x >> 6, l = threadIdx.x & 63;
  const int g = l >> 4, li = l & 15;
  const int n = blockIdx.y;
  const int i0 = blockIdx.x * 64 + w * 16;
  short8v kz = {0,0,0,0,0,0,0,0};
  short8v ka = kz;
  if (g == 0) ka = *reinterpret_cast<const short8v*>(KCB + ((size_t)n*NPIX + i0 + li)*8);
  const unsigned short* qbase = QCB + (size_t)n*NPIX*8 + li*8;
  const f32x4* wc4 = reinterpret_cast<const f32x4*>(ws + OFF_VC) + (size_t)n*NPIX + li;
  f32x4 acc0 = {0.f,0.f,0.f,0.f}, acc1 = {0.f,0.f,0.f,0.f};
  f32x4 acc2 = {0.f,0.f,0.f,0.f}, acc3 = {0.f,0.f,0.f,0.f};
#pragma unroll 4
  for (int t = 0; t < 256; ++t) {
    const int jb = t*16;
    short8v qb = *reinterpret_cast<const short8v*>(qbase + (size_t)jb*8); // Q[jb+li]
    f32x4 w4 = wc4[jb];                                                  // w[jb+li][0..3]
    f32x4 z = {0.f,0.f,0.f,0.f};
    f32x4 s = MFMA(ka, qb, z);  // reg r: S[j=jb+li][i=i0+4g+r]
    acc0 += w4 * fexp2(s[0]);
    acc1 += w4 * fexp2(s[1]);
    acc2 += w4 * fexp2(s[2]);
    acc3 += w4 * fexp2(s[3]);
  }
  // reduce over li (bits 0..3 of lane id)
#pragma unroll
  for (int m = 1; m < 16; m <<= 1) {
#pragma unroll
    for (int c = 0; c < 4; ++c) {
      acc0[c] += __shfl_xor(acc0[c], m, 64);
      acc1[c] += __shfl_xor(acc1[c], m, 64);
      acc2[c] += __shfl_xor(acc2[c], m, 64);
      acc3[c] += __shfl_xor(acc3[c], m, 64);
    }
  }
  if (li == 0) {
    f32x4* oc = reinterpret_cast<f32x4*>(ws + OFF_OUTC) + (size_t)n*NPIX + i0 + 4*g;
    oc[0] = acc0;
    oc[1] = acc1;
    oc[2] = acc2;
    oc[3] = acc3;
  }
}

// global pass B (MFMA): OUT[c][i] += sum_j WB[c][j]*exp2(S[j][i]).  grid (64, 8) x 256
__global__ __launch_bounds__(256, 2) void k_mB(float* __restrict__ ws)
{
  __shared__ unsigned int E_dw[4][16][36];
  const unsigned short* QB = reinterpret_cast<const unsigned short*>(ws + OFF_QB);
  const unsigned short* KB = reinterpret_cast<const unsigned short*>(ws + OFF_KB);
  const unsigned short* WB = reinterpret_cast<const unsigned short*>(ws + OFF_WB);
  const int w = threadIdx.x >> 6, l = threadIdx.x & 63;
  const int g = l >> 4, li = l & 15;
  const int iw = blockIdx.x * 64 + w * 16;
  const int jbase = blockIdx.y * 512;
  short8v kb[3];
#pragma unroll
  for (int kk = 0; kk < 3; ++kk)
    kb[kk] = *reinterpret_cast<const short8v*>(KB + (iw + li)*KPAD + kk*32 + 8*g);
  f32x4 accW[5];
#pragma unroll
  for (int m = 0; m < 5; ++m) accW[m] = (f32x4){0.f, 0.f, 0.f, 0.f};
  unsigned int (*Em)[36] = E_dw[w];
  for (int t = 0; t < 16; ++t) {
    const int jb = jbase + t*32;
#pragma unroll
    for (int m = 0; m < 2; ++m) {
      f32x4 acc = {0.f, 0.f, 0.f, 0.f};
#pragma unroll
      for (int kk = 0; kk < 3; ++kk) {
        short8v qa = *reinterpret_cast<const short8v*>(QB + (jb + m*16 + li)*KPAD + kk*32 + 8*g);
        acc = MFMA(qa, kb[kk], acc);
      }
      Em[li][m*8 + 2*g    ] = bf16pair(fexp2(acc[0]), fexp2(acc[1]));
      Em[li][m*8 + 2*g + 1] = bf16pair(fexp2(acc[2]), fexp2(acc[3]));
    }
    short8v eb = *reinterpret_cast<const short8v*>(&Em[li][4*g]);
#pragma unroll
    for (int m = 0; m < 5; ++m) {
      short8v wa = *reinterpret_cast<const short8v*>(WB + (m*16 + li)*NPIX + jb + 8*g);
      accW[m] = MFMA(wa, eb, accW[m]);
    }
  }
  float* OG = ws + OFF_OUTG;
#pragma unroll
  for (int m = 0; m < 5; ++m) {
#pragma unroll
    for (int r = 0; r < 4; ++r) {
      const int c = m*16 + 4*g + r;
      if (c < NCH) atomicAdd(&OG[c*NPIX + iw + li], accW[m][r]);
    }
  }
}

// pooled[n][p] = sum_r x[4n+r][p] * (outC[n][p][r] + outG[4n+r][p]).  grid (288) x 256
__global__ void k_final(const float* __restrict__ x, const float* __restrict__ ws,
                        float* __restrict__ out)
{
  const int t = blockIdx.x * blockDim.x + threadIdx.x;
  const int n = t >> 12, p = t & 4095;
  const f32x4 oc4 = reinterpret_cast<const f32x4*>(ws + OFF_OUTC)[t];
  const float* og = ws + OFF_OUTG + (size_t)n*4*NPIX;
  float s = 0.f;
#pragma unroll
  for (int r = 0; r < 4; ++r) {
    s += x[(4*n+r)*NPIX + p] * (oc4[r] + og[r*NPIX + p]);
  }
  out[t] = s;
}

extern "C" void kernel_launch(void* const* d_in, const int* in_sizes, int n_in,
                              void* d_out, int out_size, void* d_ws, size_t ws_size,
                              hipStream_t stream)
{
  const float* x   = (const float*)d_in[0];
  const float* Wq  = (const float*)d_in[1];
  const float* bq  = (const float*)d_in[2];
  const float* Wk  = (const float*)d_in[3];
  const float* bk  = (const float*)d_in[4];
  const float* Wv  = (const float*)d_in[5];
  const float* bv  = (const float*)d_in[6];
  const float* WqG = (const float*)d_in[7];
  const float* bqG = (const float*)d_in[8];
  const float* WkG = (const float*)d_in[9];
  const float* bkG = (const float*)d_in[10];
  const float* WvG = (const float*)d_in[11];
  const float* bvG = (const float*)d_in[12];
  float* ws  = (float*)d_ws;
  float* out = (float*)d_out;

  if (ws_size < (size_t)WS_FLOATS * sizeof(float)) return; // need ~9.6 MB scratch

  // zero only the atomic accumulators: DG + OUTG (contiguous)
  hipMemsetAsync(ws + OFF_DG, 0, (size_t)(4096 + NCH*NPIX) * sizeof(float), stream);

  hipLaunchKernelGGL(k_qkv, dim3(16, 24), dim3(256), 0, stream,
                     x, Wq, bq, Wk, bk, Wv, bv, WqG, bqG, WkG, bkG, WvG, bvG, ws);
  hipLaunchKernelGGL(k_cA, dim3(64, 18), dim3(256), 0, stream, ws);
  hipLaunchKernelGGL(k_mA, dim3(64, 8), dim3(256), 0, stream, ws);
  hipLaunchKernelGGL(k_wcomp, dim3(304), dim3(256), 0, stream, ws);
  hipLaunchKernelGGL(k_cB, dim3(64, 18), dim3(256), 0, stream, ws);
  hipLaunchKernelGGL(k_mB, dim3(64, 8), dim3(256), 0, stream, ws);
  hipLaunchKernelGGL(k_final, dim3(288), dim3(256), 0, stream, x, ws, out);
}

// Round 7
// 186.132 us; speedup vs baseline: 6.5731x; 1.1000x over previous
//
#include <hip/hip_runtime.h>

#define NPIX 4096
#define NCH 72
#define NCHUNK 18
#define KPAD 96

static constexpr float SCALE_LOG2E = 0.022542110013890054f; // (1/64)*log2(e)

// ws layout (float offsets)
#define OFF_VC 0          // [18][4096][4] f32 chunk v; becomes v/D in-place after k_wcomp
#define OFF_VG 294912     // [72][4096] f32 global v (c-major)
#define OFF_DC 589824     // [18][4096] f32 (direct-stored by k_cA)
#define OFF_DG 663552     // [4096] f32 (atomics; memset)
#define OFF_OUTG 667648   // [72][4096] f32 (atomics; memset, contiguous with DG)
#define OFF_OUTC 962560   // [18][4096][4] f32 (direct-stored by k_cB, pixel-major float4)
#define OFF_QB 1257472    // bf16 [4096][96] global q (scaled, zero-padded 72..95)
#define OFF_KB 1454080    // bf16 [4096][96] global k (zero-padded)
#define OFF_WB 1650688    // bf16 [80][4096] global v/D (rows 72..79 zero)
#define OFF_QCB 1814528   // bf16 [18][4096][4] chunk q (scaled), 8B/pixel
#define OFF_KCB 1961984   // bf16 [18][4096][4] chunk k, 8B/pixel
#define WS_FLOATS 2109440

typedef __attribute__((ext_vector_type(8))) short short8v;
typedef __attribute__((ext_vector_type(4))) short short4v;
typedef __attribute__((ext_vector_type(4))) float f32x4;

__device__ __forceinline__ float fexp2(float x) {
#if __has_builtin(__builtin_amdgcn_exp2f)
  return __builtin_amdgcn_exp2f(x);
#else
  return exp2f(x);
#endif
}

__device__ __forceinline__ unsigned short bf16r(float f) {
  unsigned int u = __float_as_uint(f);
  u = (u + 0x7FFFu + ((u >> 16) & 1u)) >> 16;
  return (unsigned short)u;
}
__device__ __forceinline__ unsigned int bf16pair(float lo, float hi) {
  return (unsigned int)bf16r(lo) | ((unsigned int)bf16r(hi) << 16);
}

__device__ __forceinline__ f32x4 MFMA(short8v a, short8v b, f32x4 c) {
  return __builtin_amdgcn_mfma_f32_16x16x32_bf16(a, b, c, 0, 0, 0);
}

__device__ __forceinline__ short8v expand4(short4v a) {
  short8v r = { a[0], a[1], a[2], a[3], 0, 0, 0, 0 };
  return r;
}

__device__ __forceinline__ float dot4(float4 a, float4 b) {
  return a.x*b.x + a.y*b.y + a.z*b.z + a.w*b.w;
}

__device__ __forceinline__ float4 mix4(const float* __restrict__ W, const float* __restrict__ b,
                                       float x0, float x1, float x2, float x3, float sc)
{
  float4 r;
  r.x = (b[0] + W[0]*x0  + W[1]*x1  + W[2]*x2  + W[3]*x3)  * sc;
  r.y = (b[1] + W[4]*x0  + W[5]*x1  + W[6]*x2  + W[7]*x3)  * sc;
  r.z = (b[2] + W[8]*x0  + W[9]*x1  + W[10]*x2 + W[11]*x3) * sc;
  r.w = (b[3] + W[12]*x0 + W[13]*x1 + W[14]*x2 + W[15]*x3) * sc;
  return r;
}

// grid (16, 24) x 256. seg 0..5: chunk qkv (3 chunks each). seg 6..23: global (mat m, group of 12)
__global__ __launch_bounds__(256, 3) void k_qkv(const float* __restrict__ x,
    const float* __restrict__ Wq, const float* __restrict__ bq,
    const float* __restrict__ Wk, const float* __restrict__ bk,
    const float* __restrict__ Wv, const float* __restrict__ bv,
    const float* __restrict__ WqG, const float* __restrict__ bqG,
    const float* __restrict__ WkG, const float* __restrict__ bkG,
    const float* __restrict__ WvG, const float* __restrict__ bvG,
    float* __restrict__ ws)
{
  const int p = blockIdx.x * blockDim.x + threadIdx.x;
  const int seg = blockIdx.y;
  if (seg < 6) {
    short4v* qcb = reinterpret_cast<short4v*>(ws + OFF_QCB);
    short4v* kcb = reinterpret_cast<short4v*>(ws + OFF_KCB);
    float4* vd = reinterpret_cast<float4*>(ws + OFF_VC);
    const int n0 = seg * 3;
#pragma unroll
    for (int dn = 0; dn < 3; ++dn) {
      const int n = n0 + dn;
      const float x0 = x[(4*n+0)*NPIX + p];
      const float x1 = x[(4*n+1)*NPIX + p];
      const float x2 = x[(4*n+2)*NPIX + p];
      const float x3 = x[(4*n+3)*NPIX + p];
      float4 q = mix4(Wq + n*16, bq + n*4, x0, x1, x2, x3, SCALE_LOG2E);
      float4 k = mix4(Wk + n*16, bk + n*4, x0, x1, x2, x3, 1.0f);
      float4 v = mix4(Wv + n*16, bv + n*4, x0, x1, x2, x3, 1.0f);
      short4v qs = { (short)bf16r(q.x), (short)bf16r(q.y), (short)bf16r(q.z), (short)bf16r(q.w) };
      short4v ks = { (short)bf16r(k.x), (short)bf16r(k.y), (short)bf16r(k.z), (short)bf16r(k.w) };
      qcb[(size_t)n*NPIX + p] = qs;
      kcb[(size_t)n*NPIX + p] = ks;
      vd[n*NPIX + p] = v;
    }
  } else {
    const int m = (seg - 6) / 6;
    const int g6 = (seg - 6) % 6;
    const float* W = (m == 0) ? WqG : (m == 1) ? WkG : WvG;
    const float* b = (m == 0) ? bqG : (m == 1) ? bkG : bvG;
    float4 xv[18];
#pragma unroll
    for (int c = 0; c < 18; ++c) {
      float4 t;
      t.x = x[(4*c+0)*NPIX + p];
      t.y = x[(4*c+1)*NPIX + p];
      t.z = x[(4*c+2)*NPIX + p];
      t.w = x[(4*c+3)*NPIX + p];
      xv[c] = t;
    }
    const int ob = g6 * 12;
    if (m == 2) {
      float* dst = ws + OFF_VG; // [72][4096]
      for (int o = ob; o < ob + 12; ++o) {
        float acc = b[o];
        const float4* wrow = reinterpret_cast<const float4*>(W + o*NCH);
#pragma unroll
        for (int c = 0; c < 18; ++c) acc += dot4(wrow[c], xv[c]);
        dst[o*NPIX + p] = acc;
      }
    } else {
      unsigned short* dst = reinterpret_cast<unsigned short*>(ws + ((m == 0) ? OFF_QB : OFF_KB));
      const float sc = (m == 0) ? SCALE_LOG2E : 1.0f;
      for (int o = ob; o < ob + 12; ++o) {
        float acc = b[o];
        const float4* wrow = reinterpret_cast<const float4*>(W + o*NCH);
#pragma unroll
        for (int c = 0; c < 18; ++c) acc += dot4(wrow[c], xv[c]);
        dst[p*KPAD + o] = bf16r(acc * sc);
      }
      if (g6 == 5) {
#pragma unroll
        for (int o = NCH; o < KPAD; ++o) dst[p*KPAD + o] = 0;
      }
    }
  }
}

// chunk pass A (MFMA): DC[n][j] = sum_i exp2(q_j.k_i).  grid (64, 18) x 256
// wave owns 16 j's; K-stream (8B/i) staged block-wide in LDS, double-buffered.
__global__ __launch_bounds__(256, 4) void k_cA(float* __restrict__ ws)
{
  __shared__ short4v Kt[2][256];
  const int tid = threadIdx.x;
  const int w = tid >> 6, l = tid & 63;
  const int g = l >> 4, li = l & 15;
  const int n = blockIdx.y;
  const int j0 = blockIdx.x * 64 + w * 16;
  const short4v* QCB = reinterpret_cast<const short4v*>(ws + OFF_QCB);
  const short4v* ksrc = reinterpret_cast<const short4v*>(ws + OFF_KCB) + (size_t)n*NPIX;
  short8v qa = {0,0,0,0,0,0,0,0};
  if (g == 0) qa = expand4(QCB[(size_t)n*NPIX + j0 + li]);
  float d0 = 0.f, d1 = 0.f, d2 = 0.f, d3 = 0.f;
  short4v nxt = ksrc[tid];
  for (int tb = 0; tb < 16; ++tb) {
    Kt[tb & 1][tid] = nxt;
    if (tb < 15) nxt = ksrc[(tb + 1)*256 + tid];
    __syncthreads();
    const short4v* cur = Kt[tb & 1];
#pragma unroll 8
    for (int ti = 0; ti < 16; ++ti) {
      short8v kb = expand4(cur[ti*16 + li]);
      f32x4 z = {0.f,0.f,0.f,0.f};
      f32x4 s = MFMA(qa, kb, z);
      d0 += fexp2(s[0]);
      d1 += fexp2(s[1]);
      d2 += fexp2(s[2]);
      d3 += fexp2(s[3]);
    }
  }
#pragma unroll
  for (int m = 1; m < 16; m <<= 1) {
    d0 += __shfl_xor(d0, m, 64);
    d1 += __shfl_xor(d1, m, 64);
    d2 += __shfl_xor(d2, m, 64);
    d3 += __shfl_xor(d3, m, 64);
  }
  if (li == 0) {
    float* Dc = ws + OFF_DC + n*NPIX;
    Dc[j0 + 4*g + 0] = d0;
    Dc[j0 + 4*g + 1] = d1;
    Dc[j0 + 4*g + 2] = d2;
    Dc[j0 + 4*g + 3] = d3;
  }
}

// global pass A (MFMA): D[j] = sum_i exp2(S[j][i]).  grid (64, 8) x 256
__global__ __launch_bounds__(256, 2) void k_mA(float* __restrict__ ws)
{
  const unsigned short* QB = reinterpret_cast<const unsigned short*>(ws + OFF_QB);
  const unsigned short* KB = reinterpret_cast<const unsigned short*>(ws + OFF_KB);
  const int w = threadIdx.x >> 6, l = threadIdx.x & 63;
  const int g = l >> 4, li = l & 15;
  const int j0 = blockIdx.x * 64 + w * 16;
  const int i0 = blockIdx.y * 512;
  short8v qa[3];
#pragma unroll
  for (int kk = 0; kk < 3; ++kk)
    qa[kk] = *reinterpret_cast<const short8v*>(QB + (j0 + li)*KPAD + kk*32 + 8*g);
  float ds0 = 0.f, ds1 = 0.f, ds2 = 0.f, ds3 = 0.f;
  for (int t = 0; t < 32; ++t) {
    const int i = i0 + t*16;
    f32x4 acc = {0.f, 0.f, 0.f, 0.f};
#pragma unroll
    for (int kk = 0; kk < 3; ++kk) {
      short8v kb = *reinterpret_cast<const short8v*>(KB + (i + li)*KPAD + kk*32 + 8*g);
      acc = MFMA(qa[kk], kb, acc);
    }
    ds0 += fexp2(acc[0]);
    ds1 += fexp2(acc[1]);
    ds2 += fexp2(acc[2]);
    ds3 += fexp2(acc[3]);
  }
#pragma unroll
  for (int m = 1; m < 16; m <<= 1) {
    ds0 += __shfl_xor(ds0, m, 64);
    ds1 += __shfl_xor(ds1, m, 64);
    ds2 += __shfl_xor(ds2, m, 64);
    ds3 += __shfl_xor(ds3, m, 64);
  }
  if (li == 0) {
    float* D = ws + OFF_DG;
    atomicAdd(&D[j0 + 4*g + 0], ds0);
    atomicAdd(&D[j0 + 4*g + 1], ds1);
    atomicAdd(&D[j0 + 4*g + 2], ds2);
    atomicAdd(&D[j0 + 4*g + 3], ds3);
  }
}

// w = v / D.  chunk: in-place VC /= D.  global: WB = bf16(VG/D).  grid (304) x 256
__global__ void k_wcomp(float* __restrict__ ws)
{
  const int t = blockIdx.x * blockDim.x + threadIdx.x;
  if (blockIdx.x < 288) {
    const int n = t >> 12, j = t & 4095;
    const float inv = 1.0f / ws[OFF_DC + n*NPIX + j];
    float4* vc = reinterpret_cast<float4*>(ws + OFF_VC) + ((size_t)n*NPIX + j);
    float4 v = *vc;
    v.x *= inv; v.y *= inv; v.z *= inv; v.w *= inv;
    *vc = v;
  } else {
    const int j = t - NCHUNK*NPIX; // 0..4095
    const float inv = 1.0f / ws[OFF_DG + j];
    unsigned short* WB = reinterpret_cast<unsigned short*>(ws + OFF_WB);
    const float* VG = ws + OFF_VG;
#pragma unroll
    for (int c = 0; c < NCH; ++c)
      WB[c*NPIX + j] = bf16r(VG[c*NPIX + j] * inv);
#pragma unroll
    for (int c = NCH; c < 80; ++c) WB[c*NPIX + j] = 0;
  }
}

// chunk pass B (MFMA, transpose-free): OUTC[n][i][c] = sum_j w[j][c]*exp2(q_j.k_i).
// grid (64, 18) x 256.  Wave owns 16 i (A = K-frag, fixed); j-stream (Q 8B + W 16B)
// staged block-wide in LDS, double-buffered.  PV update in registers; shfl reduce.
__global__ __launch_bounds__(256, 4) void k_cB(float* __restrict__ ws)
{
  __shared__ short4v Qt[2][256];
  __shared__ f32x4 Wt[2][256];
  const int tid = threadIdx.x;
  const int w = tid >> 6, l = tid & 63;
  const int g = l >> 4, li = l & 15;
  const int n = blockIdx.y;
  const int i0 = blockIdx.x * 64 + w * 16;
  const short4v* KCB = reinterpret_cast<const short4v*>(ws + OFF_KCB);
  const short4v* qsrc = reinterpret_cast<const short4v*>(ws + OFF_QCB) + (size_t)n*NPIX;
  const f32x4* wsrc = reinterpret_cast<const f32x4*>(ws + OFF_VC) + (size_t)n*NPIX;
  short8v ka = {0,0,0,0,0,0,0,0};
  if (g == 0) ka = expand4(KCB[(size_t)n*NPIX + i0 + li]);
  f32x4 acc0 = {0.f,0.f,0.f,0.f}, acc1 = {0.f,0.f,0.f,0.f};
  f32x4 acc2 = {0.f,0.f,0.f,0.f}, acc3 = {0.f,0.f,0.f,0.f};
  short4v qnxt = qsrc[tid];
  f32x4 wnxt = wsrc[tid];
  for (int tb = 0; tb < 16; ++tb) {
    Qt[tb & 1][tid] = qnxt;
    Wt[tb & 1][tid] = wnxt;
    if (tb < 15) {
      qnxt = qsrc[(tb + 1)*256 + tid];
      wnxt = wsrc[(tb + 1)*256 + tid];
    }
    __syncthreads();
    const short4v* qcur = Qt[tb & 1];
    const f32x4* wcur = Wt[tb & 1];
#pragma unroll 4
    for (int ti = 0; ti < 16; ++ti) {
      short8v qb = expand4(qcur[ti*16 + li]);
      f32x4 w4 = wcur[ti*16 + li];
      f32x4 z = {0.f,0.f,0.f,0.f};
      f32x4 s = MFMA(ka, qb, z);  // reg r: S[j][i0+4g+r], j = tb*256+ti*16+li
      acc0 += w4 * fexp2(s[0]);
      acc1 += w4 * fexp2(s[1]);
      acc2 += w4 * fexp2(s[2]);
      acc3 += w4 * fexp2(s[3]);
    }
  }
  // reduce over li (bits 0..3 of lane id)
#pragma unroll
  for (int m = 1; m < 16; m <<= 1) {
#pragma unroll
    for (int c = 0; c < 4; ++c) {
      acc0[c] += __shfl_xor(acc0[c], m, 64);
      acc1[c] += __shfl_xor(acc1[c], m, 64);
      acc2[c] += __shfl_xor(acc2[c], m, 64);
      acc3[c] += __shfl_xor(acc3[c], m, 64);
    }
  }
  if (li == 0) {
    f32x4* oc = reinterpret_cast<f32x4*>(ws + OFF_OUTC) + (size_t)n*NPIX + i0 + 4*g;
    oc[0] = acc0;
    oc[1] = acc1;
    oc[2] = acc2;
    oc[3] = acc3;
  }
}

// global pass B (MFMA): OUT[c][i] += sum_j WB[c][j]*exp2(S[j][i]).  grid (64, 8) x 256
__global__ __launch_bounds__(256, 2) void k_mB(float* __restrict__ ws)
{
  __shared__ unsigned int E_dw[4][16][36];
  const unsigned short* QB = reinterpret_cast<const unsigned short*>(ws + OFF_QB);
  const unsigned short* KB = reinterpret_cast<const unsigned short*>(ws + OFF_KB);
  const unsigned short* WB = reinterpret_cast<const unsigned short*>(ws + OFF_WB);
  const int w = threadIdx.x >> 6, l = threadIdx.x & 63;
  const int g = l >> 4, li = l & 15;
  const int iw = blockIdx.x * 64 + w * 16;
  const int jbase = blockIdx.y * 512;
  short8v kb[3];
#pragma unroll
  for (int kk = 0; kk < 3; ++kk)
    kb[kk] = *reinterpret_cast<const short8v*>(KB + (iw + li)*KPAD + kk*32 + 8*g);
  f32x4 accW[5];
#pragma unroll
  for (int m = 0; m < 5; ++m) accW[m] = (f32x4){0.f, 0.f, 0.f, 0.f};
  unsigned int (*Em)[36] = E_dw[w];
  for (int t = 0; t < 16; ++t) {
    const int jb = jbase + t*32;
#pragma unroll
    for (int m = 0; m < 2; ++m) {
      f32x4 acc = {0.f, 0.f, 0.f, 0.f};
#pragma unroll
      for (int kk = 0; kk < 3; ++kk) {
        short8v qa = *reinterpret_cast<const short8v*>(QB + (jb + m*16 + li)*KPAD + kk*32 + 8*g);
        acc = MFMA(qa, kb[kk], acc);
      }
      Em[li][m*8 + 2*g    ] = bf16pair(fexp2(acc[0]), fexp2(acc[1]));
      Em[li][m*8 + 2*g + 1] = bf16pair(fexp2(acc[2]), fexp2(acc[3]));
    }
    short8v eb = *reinterpret_cast<const short8v*>(&Em[li][4*g]);
#pragma unroll
    for (int m = 0; m < 5; ++m) {
      short8v wa = *reinterpret_cast<const short8v*>(WB + (m*16 + li)*NPIX + jb + 8*g);
      accW[m] = MFMA(wa, eb, accW[m]);
    }
  }
  float* OG = ws + OFF_OUTG;
#pragma unroll
  for (int m = 0; m < 5; ++m) {
#pragma unroll
    for (int r = 0; r < 4; ++r) {
      const int c = m*16 + 4*g + r;
      if (c < NCH) atomicAdd(&OG[c*NPIX + iw + li], accW[m][r]);
    }
  }
}

// pooled[n][p] = sum_r x[4n+r][p] * (outC[n][p][r] + outG[4n+r][p]).  grid (288) x 256
__global__ void k_final(const float* __restrict__ x, const float* __restrict__ ws,
                        float* __restrict__ out)
{
  const int t = blockIdx.x * blockDim.x + threadIdx.x;
  const int n = t >> 12, p = t & 4095;
  const f32x4 oc4 = reinterpret_cast<const f32x4*>(ws + OFF_OUTC)[t];
  const float* og = ws + OFF_OUTG + (size_t)n*4*NPIX;
  float s = 0.f;
#pragma unroll
  for (int r = 0; r < 4; ++r) {
    s += x[(4*n+r)*NPIX + p] * (oc4[r] + og[r*NPIX + p]);
  }
  out[t] = s;
}

extern "C" void kernel_launch(void* const* d_in, const int* in_sizes, int n_in,
                              void* d_out, int out_size, void* d_ws, size_t ws_size,
                              hipStream_t stream)
{
  const float* x   = (const float*)d_in[0];
  const float* Wq  = (const float*)d_in[1];
  const float* bq  = (const float*)d_in[2];
  const float* Wk  = (const float*)d_in[3];
  const float* bk  = (const float*)d_in[4];
  const float* Wv  = (const float*)d_in[5];
  const float* bv  = (const float*)d_in[6];
  const float* WqG = (const float*)d_in[7];
  const float* bqG = (const float*)d_in[8];
  const float* WkG = (const float*)d_in[9];
  const float* bkG = (const float*)d_in[10];
  const float* WvG = (const float*)d_in[11];
  const float* bvG = (const float*)d_in[12];
  float* ws  = (float*)d_ws;
  float* out = (float*)d_out;

  if (ws_size < (size_t)WS_FLOATS * sizeof(float)) return; // need ~8.4 MB scratch

  // zero only the atomic accumulators: DG + OUTG (contiguous)
  hipMemsetAsync(ws + OFF_DG, 0, (size_t)(4096 + NCH*NPIX) * sizeof(float), stream);

  hipLaunchKernelGGL(k_qkv, dim3(16, 24), dim3(256), 0, stream,
                     x, Wq, bq, Wk, bk, Wv, bv, WqG, bqG, WkG, bkG, WvG, bvG, ws);
  hipLaunchKernelGGL(k_cA, dim3(64, 18), dim3(256), 0, stream, ws);
  hipLaunchKernelGGL(k_mA, dim3(64, 8), dim3(256), 0, stream, ws);
  hipLaunchKernelGGL(k_wcomp, dim3(304), dim3(256), 0, stream, ws);
  hipLaunchKernelGGL(k_cB, dim3(64, 18), dim3(256), 0, stream, ws);
  hipLaunchKernelGGL(k_mB, dim3(64, 8), dim3(256), 0, stream, ws);
  hipLaunchKernelGGL(k_final, dim3(288), dim3(256), 0, stream, x, ws, out);
}